// Round 16
// baseline (2014.910 us; speedup 1.0000x reference)
//
#include <hip/hip_runtime.h>
#include <hip/hip_fp16.h>

// Problem constants
#define BB 64
#define TT 2048
#define II 128
#define HH 128
#define NG 512   // 4*H
#define CH 128   // pipeline chunk (steps)
#define NCH (TT / CH)
#define LEAD 4   // A's chunk lead (prologue covers chunks 0..LEAD-1)
#define DYN_LDS 81984  // > 160KiB/2 -> hardware places only ONE WG per CU

typedef _Float16 h2_t __attribute__((ext_vector_type(2)));

#if defined(__has_builtin)
#if __has_builtin(__builtin_amdgcn_fdot2)
#define HAVE_FDOT2 1
#endif
#endif

__device__ __forceinline__ float fdot2f(h2_t a, h2_t b, float c) {
#ifdef HAVE_FDOT2
  return __builtin_amdgcn_fdot2(a, b, c, false);
#else
  return c + (float)a[0] * (float)b[0] + (float)a[1] * (float)b[1];
#endif
}

// packed f16 FMA: clang lowers elementwise h2_t a*b+c to v_pk_fma_f16.
__device__ __forceinline__ h2_t pkfma(h2_t a, h2_t b, h2_t c) {
  return a * b + c;
}

__device__ __forceinline__ float fast_sigmoid(float x) {
  float t = __builtin_amdgcn_exp2f(-1.4426950408889634f * x);
  return __builtin_amdgcn_rcpf(1.0f + t);
}
__device__ __forceinline__ float act_gate(float x, bool tanh_sel) {
  float xx = tanh_sel ? 2.0f * x : x;
  float s = fast_sigmoid(xx);
  return tanh_sel ? 2.0f * s - 1.0f : s;
}
__device__ __forceinline__ float fast_tanh(float x) {
  return 2.0f * fast_sigmoid(2.0f * x) - 1.0f;
}

__device__ __forceinline__ float dpp_xor1(float x) {
  return __int_as_float(__builtin_amdgcn_update_dpp(0, __float_as_int(x), 0xB1, 0xF, 0xF, true));
}
__device__ __forceinline__ float dpp_xor2(float x) {
  return __int_as_float(__builtin_amdgcn_update_dpp(0, __float_as_int(x), 0x4E, 0xF, 0xF, true));
}

// LDS-only barrier: lgkmcnt drain + s_barrier (no vmcnt drain).
__device__ __forceinline__ void bar_lds() {
  __builtin_amdgcn_fence(__ATOMIC_RELEASE, "workgroup", "local");
  __builtin_amdgcn_s_barrier();
  __builtin_amdgcn_fence(__ATOMIC_ACQUIRE, "workgroup", "local");
}

union LD4 {
  float4 f4;
  h2_t h[4];
};
union LDB {
  uint4 u4;
  h2_t h[4];
};

__device__ __forceinline__ unsigned aload(unsigned* p) { return atomicAdd(p, 0u); }

// ---------------------------------------------------------------------------
// Transpose both Wx0 and Wx1: [512][128] -> [128][512]
// ---------------------------------------------------------------------------
__global__ void w_transpose2(const float* __restrict__ W0, float* __restrict__ T0,
                             const float* __restrict__ W1, float* __restrict__ T1) {
  int bid = blockIdx.x;
  const float* W = (bid < 256) ? W0 : W1;
  float* T = (bid < 256) ? T0 : T1;
  int idx = (bid & 255) * 256 + threadIdx.x;
  int n = idx >> 7;
  int k = idx & 127;
  T[k * NG + n] = W[idx];
}

// ---------------------------------------------------------------------------
// Prologue GEMM: Xg0 for chunks 0..LEAD-1 (rows [b*TT, b*TT+LEAD*CH)).
// ---------------------------------------------------------------------------
__global__ __launch_bounds__(256) void xg_gemm_pro(const float* __restrict__ X,
                                                   const float* __restrict__ WT,
                                                   const float* __restrict__ bias,
                                                   __half* __restrict__ Xg) {
  __shared__ float As[64][132];
  __shared__ float Bs[128][64];
  const int bx = blockIdx.x;
  const size_t m0 = (size_t)(bx >> 3) * TT + (bx & 7) * 64;
  const int n0 = blockIdx.y * 64;
  const int tid = threadIdx.x;

  {
    const float4* xv = (const float4*)(X + m0 * II);
#pragma unroll
    for (int r = 0; r < 8; ++r) {
      int f = tid + 256 * r;
      int m = f >> 5;
      int c4 = f & 31;
      float4 v = xv[m * 32 + c4];
      *(float4*)&As[m][c4 * 4] = v;
    }
  }
  {
#pragma unroll
    for (int r = 0; r < 8; ++r) {
      int f = tid + 256 * r;
      int k = f >> 4;
      int q = f & 15;
      float4 v = *(const float4*)(WT + (size_t)k * NG + n0 + q * 4);
      *(float4*)&Bs[k][q * 4] = v;
    }
  }
  __syncthreads();

  const int tx = tid & 15;
  const int ty = tid >> 4;
  float acc[4][4];
#pragma unroll
  for (int i = 0; i < 4; ++i)
#pragma unroll
    for (int j = 0; j < 4; ++j) acc[i][j] = 0.0f;

#pragma unroll 4
  for (int k = 0; k < 128; ++k) {
    float a0 = As[ty * 4 + 0][k];
    float a1 = As[ty * 4 + 1][k];
    float a2 = As[ty * 4 + 2][k];
    float a3 = As[ty * 4 + 3][k];
    float4 bv = *(const float4*)&Bs[k][tx * 4];
    acc[0][0] = fmaf(a0, bv.x, acc[0][0]);
    acc[0][1] = fmaf(a0, bv.y, acc[0][1]);
    acc[0][2] = fmaf(a0, bv.z, acc[0][2]);
    acc[0][3] = fmaf(a0, bv.w, acc[0][3]);
    acc[1][0] = fmaf(a1, bv.x, acc[1][0]);
    acc[1][1] = fmaf(a1, bv.y, acc[1][1]);
    acc[1][2] = fmaf(a1, bv.z, acc[1][2]);
    acc[1][3] = fmaf(a1, bv.w, acc[1][3]);
    acc[2][0] = fmaf(a2, bv.x, acc[2][0]);
    acc[2][1] = fmaf(a2, bv.y, acc[2][1]);
    acc[2][2] = fmaf(a2, bv.z, acc[2][2]);
    acc[2][3] = fmaf(a2, bv.w, acc[2][3]);
    acc[3][0] = fmaf(a3, bv.x, acc[3][0]);
    acc[3][1] = fmaf(a3, bv.y, acc[3][1]);
    acc[3][2] = fmaf(a3, bv.z, acc[3][2]);
    acc[3][3] = fmaf(a3, bv.w, acc[3][3]);
  }

  float4 bvec = *(const float4*)(bias + n0 + tx * 4);
#pragma unroll
  for (int i = 0; i < 4; ++i) {
    size_t m = m0 + ty * 4 + i;
    __half2* dst = (__half2*)(Xg + m * NG + n0 + tx * 4);
    dst[0] = __halves2half2(__float2half(acc[i][0] + bvec.x),
                            __float2half(acc[i][1] + bvec.y));
    dst[1] = __halves2half2(__float2half(acc[i][2] + bvec.z),
                            __float2half(acc[i][3] + bvec.w));
  }
}

// ===========================================================================
// Mega kernel: 256 WGs, ONE per CU (dynamic LDS > 160KiB/2).
//   [0,64):    role A — L0 recurrence (waits flagX for cc>=LEAD), flag0/chunk
//   [64,192):  role C — per iter cc: Xg0(cc+LEAD) -> flagX, then wait
//              flag0(cc) -> Xg1(cc)=h0@Wx1^T+b1 (in place) -> flagC
//   [192,256): role B — L1 recurrence on Xg1 chunks (waits flagC>=2)
// Recurrence inner product: v_pk_fma_f16 (full-rate packed ALU) instead of
// v_dot2_f32_f16 (measured ~6cyc issue) -> dot-phase issue /3.
// ===========================================================================

// ---- role A: layer-0 recurrence (pk_fma inner product) ----
__device__ __forceinline__ void roleA(int b, int n, char* smem,
    const __half* Xg, const float* __restrict__ Wh0,
    float* __restrict__ out, __half* hstream,
    unsigned* flag0, unsigned* flagX)
{
  const int j = n >> 2;
  const int p = n & 3;
  const bool tsel = (p == 2);

  h2_t wh[4][16];
#pragma unroll
  for (int g = 0; g < 4; ++g) {
    const float2* ph = (const float2*)(Wh0 + (size_t)(g * 128 + j) * HH + p * 32);
#pragma unroll
    for (int k = 0; k < 16; ++k) {
      float2 v = ph[k];
      wh[g][k][0] = (_Float16)v.x;
      wh[g][k][1] = (_Float16)v.y;
    }
  }

  _Float16(*hb)[HH] = (_Float16(*)[HH])smem;
  if (n < HH) {
    hb[0][n] = (_Float16)0.0f;
    hb[1][n] = (_Float16)0.0f;
  }
  float c = 0.0f, hv = 0.0f;
  __syncthreads();

  const __half* xs = Xg + (size_t)b * TT * NG + p * 128 + j;
  float* hT = out + (size_t)BB * TT * HH;
  float* cT = hT + 2 * BB * HH;
  __half* hsp = hstream + (size_t)b * TT * HH + j;

  const h2_t z2 = {(_Float16)0.0f, (_Float16)0.0f};

#pragma unroll 1
  for (int cc = 0; cc < NCH; ++cc) {
    if (cc >= LEAD) {
      if (n == 0) {
        while (aload(flagX + b * NCH + cc) < 2u) __builtin_amdgcn_s_sleep(1);
      }
      __syncthreads();
      __builtin_amdgcn_fence(__ATOMIC_ACQUIRE, "agent");
    }
    __half xg_c = xs[(size_t)(cc * CH) * NG];

#pragma unroll 1
    for (int s = 0; s < CH; ++s) {
      const int i = cc * CH + s;
      __half xg_n = (s + 1 < CH) ? xs[(size_t)(i + 1) * NG] : __float2half(0.0f);

      const char* H = (const char*)hb[i & 1] + p * 64;
      // 8 packed-f16 chains (2 per gate row), combined in f32 at the end
      h2_t c00 = z2, c01 = z2, c10 = z2, c11 = z2;
      h2_t c20 = z2, c21 = z2, c30 = z2, c31 = z2;
#pragma unroll
      for (int q = 0; q < 4; ++q) {
        LD4 u;
        u.f4 = *(const float4*)(H + q * 16);
        const int m = q * 4;
        c00 = pkfma(wh[0][m + 0], u.h[0], c00);
        c10 = pkfma(wh[1][m + 0], u.h[0], c10);
        c20 = pkfma(wh[2][m + 0], u.h[0], c20);
        c30 = pkfma(wh[3][m + 0], u.h[0], c30);
        c01 = pkfma(wh[0][m + 2], u.h[2], c01);
        c11 = pkfma(wh[1][m + 2], u.h[2], c11);
        c21 = pkfma(wh[2][m + 2], u.h[2], c21);
        c31 = pkfma(wh[3][m + 2], u.h[2], c31);
        c00 = pkfma(wh[0][m + 1], u.h[1], c00);
        c10 = pkfma(wh[1][m + 1], u.h[1], c10);
        c20 = pkfma(wh[2][m + 1], u.h[1], c20);
        c30 = pkfma(wh[3][m + 1], u.h[1], c30);
        c01 = pkfma(wh[0][m + 3], u.h[3], c01);
        c11 = pkfma(wh[1][m + 3], u.h[3], c11);
        c21 = pkfma(wh[2][m + 3], u.h[3], c21);
        c31 = pkfma(wh[3][m + 3], u.h[3], c31);
      }
      float a0 = ((float)c00[0] + (float)c00[1]) + ((float)c01[0] + (float)c01[1]);
      float a1 = ((float)c10[0] + (float)c10[1]) + ((float)c11[0] + (float)c11[1]);
      float a2 = ((float)c20[0] + (float)c20[1]) + ((float)c21[0] + (float)c21[1]);
      float a3 = ((float)c30[0] + (float)c30[1]) + ((float)c31[0] + (float)c31[1]);

      float k01 = (p & 1) ? a1 : a0;
      float u01 = (p & 1) ? a0 : a1;
      float r01 = k01 + dpp_xor1(u01);
      float k23 = (p & 1) ? a3 : a2;
      float u23 = (p & 1) ? a2 : a3;
      float r23 = k23 + dpp_xor1(u23);
      float kA = (p & 2) ? r23 : r01;
      float uA = (p & 2) ? r01 : r23;
      float sL = kA + dpp_xor2(uA);
      float aL = act_gate(sL + __half2float(xg_c), tsel);
      float fg = dpp_xor1(aL);
      float gg = dpp_xor2(aL);
      float og = dpp_xor2(fg);
      if (p == 0) {
        c = fg * c + aL * gg;
        hv = og * fast_tanh(c);
        _Float16 hf = (_Float16)hv;
        hb[(i & 1) ^ 1][j] = hf;
        *(_Float16*)(hsp + (size_t)i * HH) = hf;
      }
      bar_lds();
      xg_c = xg_n;
    }
    __syncthreads();   // drains hstream stores (vmcnt)
    if (n == 0) {
      __builtin_amdgcn_fence(__ATOMIC_RELEASE, "agent");
      atomicExch(flag0 + b * NCH + cc, 1u);
    }
  }

  if (p == 0) {
    hT[b * HH + j] = hv;
    cT[b * HH + j] = c;
  }
}

// ---- role C: Xg0(cc+LEAD) production then Xg1(cc) bridge GEMM ----
__device__ __forceinline__ void roleC(int cidx, int n, char* smem,
    __half* Xg, const __half* hstream, const float* __restrict__ x,
    const float* __restrict__ WT0, const float* __restrict__ b0,
    const float* __restrict__ WT1, const float* __restrict__ b1,
    unsigned* flag0, unsigned* flagC, unsigned* flagX)
{
  const int b = cidx >> 1;
  const int half = cidx & 1;
  h2_t(*As2)[68] = (h2_t(*)[68])smem;                    // [64][68] h2
  h2_t(*Bs2)[64] = (h2_t(*)[64])(smem + 64 * 68 * 4);    // [64][64] h2

  const int ty = n >> 4;
  const int tx = n & 15;
  const int mf = n >> 3;   // fill row
  const int sf = n & 7;    // fill segment

#pragma unroll 1
  for (int cc = 0; cc < NCH; ++cc) {
    // ======== part X0: Xg0 for chunk cc+LEAD (input-only, no waits) ========
    if (cc + LEAD < NCH) {
      const int t0x = (cc + LEAD) * CH + half * 64;
      {
        const float4* sx = (const float4*)(x + ((size_t)b * TT + t0x + mf) * II + sf * 16);
        float4 p0 = sx[0], p1 = sx[1], p2 = sx[2], p3 = sx[3];
        h2_t r[8];
        r[0][0] = (_Float16)p0.x; r[0][1] = (_Float16)p0.y;
        r[1][0] = (_Float16)p0.z; r[1][1] = (_Float16)p0.w;
        r[2][0] = (_Float16)p1.x; r[2][1] = (_Float16)p1.y;
        r[3][0] = (_Float16)p1.z; r[3][1] = (_Float16)p1.w;
        r[4][0] = (_Float16)p2.x; r[4][1] = (_Float16)p2.y;
        r[5][0] = (_Float16)p2.z; r[5][1] = (_Float16)p2.w;
        r[6][0] = (_Float16)p3.x; r[6][1] = (_Float16)p3.y;
        r[7][0] = (_Float16)p3.z; r[7][1] = (_Float16)p3.w;
        *(uint4*)&As2[mf][sf * 8] = *(uint4*)&r[0];
        *(uint4*)&As2[mf][sf * 8 + 4] = *(uint4*)&r[4];
      }
#pragma unroll 1
      for (int nt = 0; nt < 8; ++nt) {
        __syncthreads();
        {
          const int kp = n >> 3, cg = n & 7;
          const float4* w0 = (const float4*)(WT0 + (size_t)(2 * kp) * NG + nt * 64 + cg * 8);
          const float4* w1 = (const float4*)(WT0 + (size_t)(2 * kp + 1) * NG + nt * 64 + cg * 8);
          float4 x0 = w0[0], x1 = w0[1];
          float4 y0 = w1[0], y1 = w1[1];
          h2_t r[8];
          r[0][0] = (_Float16)x0.x; r[0][1] = (_Float16)y0.x;
          r[1][0] = (_Float16)x0.y; r[1][1] = (_Float16)y0.y;
          r[2][0] = (_Float16)x0.z; r[2][1] = (_Float16)y0.z;
          r[3][0] = (_Float16)x0.w; r[3][1] = (_Float16)y0.w;
          r[4][0] = (_Float16)x1.x; r[4][1] = (_Float16)y1.x;
          r[5][0] = (_Float16)x1.y; r[5][1] = (_Float16)y1.y;
          r[6][0] = (_Float16)x1.z; r[6][1] = (_Float16)y1.z;
          r[7][0] = (_Float16)x1.w; r[7][1] = (_Float16)y1.w;
          *(uint4*)&Bs2[kp][cg * 8] = *(uint4*)&r[0];
          *(uint4*)&Bs2[kp][cg * 8 + 4] = *(uint4*)&r[4];
        }
        __syncthreads();

        float acc[2][4];
#pragma unroll
        for (int r = 0; r < 2; ++r)
#pragma unroll
          for (int q = 0; q < 4; ++q) acc[r][q] = 0.0f;
#pragma unroll 4
        for (int k4 = 0; k4 < 16; ++k4) {
          LDB ua0, ua1;
          ua0.u4 = *(const uint4*)&As2[ty * 2][k4 * 4];
          ua1.u4 = *(const uint4*)&As2[ty * 2 + 1][k4 * 4];
#pragma unroll
          for (int t = 0; t < 4; ++t) {
            LDB ub;
            ub.u4 = *(const uint4*)&Bs2[k4 * 4 + t][tx * 4];
            acc[0][0] = fdot2f(ua0.h[t], ub.h[0], acc[0][0]);
            acc[0][1] = fdot2f(ua0.h[t], ub.h[1], acc[0][1]);
            acc[0][2] = fdot2f(ua0.h[t], ub.h[2], acc[0][2]);
            acc[0][3] = fdot2f(ua0.h[t], ub.h[3], acc[0][3]);
            acc[1][0] = fdot2f(ua1.h[t], ub.h[0], acc[1][0]);
            acc[1][1] = fdot2f(ua1.h[t], ub.h[1], acc[1][1]);
            acc[1][2] = fdot2f(ua1.h[t], ub.h[2], acc[1][2]);
            acc[1][3] = fdot2f(ua1.h[t], ub.h[3], acc[1][3]);
          }
        }
        const int col = nt * 64 + tx * 4;
        float4 bv = *(const float4*)(b0 + col);
#pragma unroll
        for (int r = 0; r < 2; ++r) {
          __half2* d = (__half2*)(Xg + ((size_t)b * TT + t0x + ty * 2 + r) * NG + col);
          d[0] = __halves2half2(__float2half(acc[r][0] + bv.x),
                                __float2half(acc[r][1] + bv.y));
          d[1] = __halves2half2(__float2half(acc[r][2] + bv.z),
                                __float2half(acc[r][3] + bv.w));
        }
      }
      __syncthreads();   // drain Xg0 stores + protect As2
      if (n == 0) {
        __builtin_amdgcn_fence(__ATOMIC_RELEASE, "agent");
        atomicAdd(flagX + b * NCH + cc + LEAD, 1u);
      }
    }

    // ======== part X1: Xg1 for chunk cc (waits on h0) ========
    if (n == 0) {
      while (aload(flag0 + b * NCH + cc) < 1u) __builtin_amdgcn_s_sleep(8);
    }
    __syncthreads();
    __builtin_amdgcn_fence(__ATOMIC_ACQUIRE, "agent");

    const int t0 = cc * CH + half * 64;
    {
      const uint4* src = (const uint4*)(hstream + ((size_t)b * TT + t0 + mf) * HH + sf * 16);
      uint4 v0 = src[0], v1 = src[1];
      *(uint4*)&As2[mf][sf * 8] = v0;
      *(uint4*)&As2[mf][sf * 8 + 4] = v1;
    }
#pragma unroll 1
    for (int nt = 0; nt < 8; ++nt) {
      __syncthreads();
      {
        const int kp = n >> 3, cg = n & 7;
        const float4* w0 = (const float4*)(WT1 + (size_t)(2 * kp) * NG + nt * 64 + cg * 8);
        const float4* w1 = (const float4*)(WT1 + (size_t)(2 * kp + 1) * NG + nt * 64 + cg * 8);
        float4 x0 = w0[0], x1 = w0[1];
        float4 y0 = w1[0], y1 = w1[1];
        h2_t r[8];
        r[0][0] = (_Float16)x0.x; r[0][1] = (_Float16)y0.x;
        r[1][0] = (_Float16)x0.y; r[1][1] = (_Float16)y0.y;
        r[2][0] = (_Float16)x0.z; r[2][1] = (_Float16)y0.z;
        r[3][0] = (_Float16)x0.w; r[3][1] = (_Float16)y0.w;
        r[4][0] = (_Float16)x1.x; r[4][1] = (_Float16)y1.x;
        r[5][0] = (_Float16)x1.y; r[5][1] = (_Float16)y1.y;
        r[6][0] = (_Float16)x1.z; r[6][1] = (_Float16)y1.z;
        r[7][0] = (_Float16)x1.w; r[7][1] = (_Float16)y1.w;
        *(uint4*)&Bs2[kp][cg * 8] = *(uint4*)&r[0];
        *(uint4*)&Bs2[kp][cg * 8 + 4] = *(uint4*)&r[4];
      }
      __syncthreads();

      float acc[2][4];
#pragma unroll
      for (int r = 0; r < 2; ++r)
#pragma unroll
        for (int q = 0; q < 4; ++q) acc[r][q] = 0.0f;
#pragma unroll 4
      for (int k4 = 0; k4 < 16; ++k4) {
        LDB ua0, ua1;
        ua0.u4 = *(const uint4*)&As2[ty * 2][k4 * 4];
        ua1.u4 = *(const uint4*)&As2[ty * 2 + 1][k4 * 4];
#pragma unroll
        for (int t = 0; t < 4; ++t) {
          LDB ub;
          ub.u4 = *(const uint4*)&Bs2[k4 * 4 + t][tx * 4];
          acc[0][0] = fdot2f(ua0.h[t], ub.h[0], acc[0][0]);
          acc[0][1] = fdot2f(ua0.h[t], ub.h[1], acc[0][1]);
          acc[0][2] = fdot2f(ua0.h[t], ub.h[2], acc[0][2]);
          acc[0][3] = fdot2f(ua0.h[t], ub.h[3], acc[0][3]);
          acc[1][0] = fdot2f(ua1.h[t], ub.h[0], acc[1][0]);
          acc[1][1] = fdot2f(ua1.h[t], ub.h[1], acc[1][1]);
          acc[1][2] = fdot2f(ua1.h[t], ub.h[2], acc[1][2]);
          acc[1][3] = fdot2f(ua1.h[t], ub.h[3], acc[1][3]);
        }
      }
      const int col = nt * 64 + tx * 4;
      float4 bv = *(const float4*)(b1 + col);
#pragma unroll
      for (int r = 0; r < 2; ++r) {
        __half2* d = (__half2*)(Xg + ((size_t)b * TT + t0 + ty * 2 + r) * NG + col);
        d[0] = __halves2half2(__float2half(acc[r][0] + bv.x),
                              __float2half(acc[r][1] + bv.y));
        d[1] = __halves2half2(__float2half(acc[r][2] + bv.z),
                              __float2half(acc[r][3] + bv.w));
      }
    }
    __syncthreads();
    if (n == 0) {
      __builtin_amdgcn_fence(__ATOMIC_RELEASE, "agent");
      atomicAdd(flagC + b * NCH + cc, 1u);
    }
  }
}

// ---- role B: layer-1 recurrence (pk_fma inner product) ----
__device__ __forceinline__ void roleB(int b, int n, char* smem,
    const __half* Xg, const float* __restrict__ Wh1,
    float* __restrict__ out, unsigned* flagC)
{
  const int j = n >> 2;
  const int p = n & 3;
  const bool tsel = (p == 2);

  h2_t wh[4][16];
#pragma unroll
  for (int g = 0; g < 4; ++g) {
    const float2* ph = (const float2*)(Wh1 + (size_t)(g * 128 + j) * HH + p * 32);
#pragma unroll
    for (int k = 0; k < 16; ++k) {
      float2 v = ph[k];
      wh[g][k][0] = (_Float16)v.x;
      wh[g][k][1] = (_Float16)v.y;
    }
  }

  _Float16(*hb)[HH] = (_Float16(*)[HH])smem;
  if (n < HH) {
    hb[0][n] = (_Float16)0.0f;
    hb[1][n] = (_Float16)0.0f;
  }
  float c = 0.0f, hv = 0.0f;
  __syncthreads();

  const __half* xs = Xg + (size_t)b * TT * NG + p * 128 + j;
  float* outp = out + (size_t)b * TT * HH;
  float* hT = out + (size_t)BB * TT * HH;
  float* cT = hT + 2 * BB * HH;

  const h2_t z2 = {(_Float16)0.0f, (_Float16)0.0f};

#pragma unroll 1
  for (int cc = 0; cc < NCH; ++cc) {
    if (n == 0) {
      while (aload(flagC + b * NCH + cc) < 2u) __builtin_amdgcn_s_sleep(8);
    }
    __syncthreads();
    __builtin_amdgcn_fence(__ATOMIC_ACQUIRE, "agent");

    __half xg_c = xs[(size_t)(cc * CH) * NG];
#pragma unroll 1
    for (int s = 0; s < CH; ++s) {
      const int i = cc * CH + s;
      __half xg_n = (s + 1 < CH) ? xs[(size_t)(i + 1) * NG] : __float2half(0.0f);

      const char* H = (const char*)hb[i & 1] + p * 64;
      h2_t c00 = z2, c01 = z2, c10 = z2, c11 = z2;
      h2_t c20 = z2, c21 = z2, c30 = z2, c31 = z2;
#pragma unroll
      for (int q = 0; q < 4; ++q) {
        LD4 u;
        u.f4 = *(const float4*)(H + q * 16);
        const int m = q * 4;
        c00 = pkfma(wh[0][m + 0], u.h[0], c00);
        c10 = pkfma(wh[1][m + 0], u.h[0], c10);
        c20 = pkfma(wh[2][m + 0], u.h[0], c20);
        c30 = pkfma(wh[3][m + 0], u.h[0], c30);
        c01 = pkfma(wh[0][m + 2], u.h[2], c01);
        c11 = pkfma(wh[1][m + 2], u.h[2], c11);
        c21 = pkfma(wh[2][m + 2], u.h[2], c21);
        c31 = pkfma(wh[3][m + 2], u.h[2], c31);
        c00 = pkfma(wh[0][m + 1], u.h[1], c00);
        c10 = pkfma(wh[1][m + 1], u.h[1], c10);
        c20 = pkfma(wh[2][m + 1], u.h[1], c20);
        c30 = pkfma(wh[3][m + 1], u.h[1], c30);
        c01 = pkfma(wh[0][m + 3], u.h[3], c01);
        c11 = pkfma(wh[1][m + 3], u.h[3], c11);
        c21 = pkfma(wh[2][m + 3], u.h[3], c21);
        c31 = pkfma(wh[3][m + 3], u.h[3], c31);
      }
      float a0 = ((float)c00[0] + (float)c00[1]) + ((float)c01[0] + (float)c01[1]);
      float a1 = ((float)c10[0] + (float)c10[1]) + ((float)c11[0] + (float)c11[1]);
      float a2 = ((float)c20[0] + (float)c20[1]) + ((float)c21[0] + (float)c21[1]);
      float a3 = ((float)c30[0] + (float)c30[1]) + ((float)c31[0] + (float)c31[1]);

      float k01 = (p & 1) ? a1 : a0;
      float u01 = (p & 1) ? a0 : a1;
      float r01 = k01 + dpp_xor1(u01);
      float k23 = (p & 1) ? a3 : a2;
      float u23 = (p & 1) ? a2 : a3;
      float r23 = k23 + dpp_xor1(u23);
      float kA = (p & 2) ? r23 : r01;
      float uA = (p & 2) ? r01 : r23;
      float sL = kA + dpp_xor2(uA);
      float aL = act_gate(sL + __half2float(xg_c), tsel);
      float fg = dpp_xor1(aL);
      float gg = dpp_xor2(aL);
      float og = dpp_xor2(fg);
      if (p == 0) {
        c = fg * c + aL * gg;
        hv = og * fast_tanh(c);
        hb[(i & 1) ^ 1][j] = (_Float16)hv;
        outp[(size_t)i * HH + j] = hv;
      }
      bar_lds();
      xg_c = xg_n;
    }
  }

  if (p == 0) {
    hT[BB * HH + b * HH + j] = hv;
    cT[BB * HH + b * HH + j] = c;
  }
}

__global__
__attribute__((amdgpu_flat_work_group_size(512, 512)))
void lstm_mega(__half* Xg, __half* hstream, const float* __restrict__ x,
               const float* __restrict__ Wh0,
               const float* __restrict__ Wh1,
               const float* __restrict__ WT0,
               const float* __restrict__ b0,
               const float* __restrict__ WT1,
               const float* __restrict__ b1,
               float* __restrict__ out,
               unsigned* flag0, unsigned* flagC, unsigned* flagX)
{
  extern __shared__ __align__(16) char smem[];   // DYN_LDS bytes: 1 WG/CU
  const int bid = blockIdx.x;
  const int n = threadIdx.x;
  if (bid < BB) {
    roleA(bid, n, smem, Xg, Wh0, out, hstream, flag0, flagX);
  } else if (bid < BB + 2 * BB) {
    roleC(bid - BB, n, smem, Xg, hstream, x, WT0, b0, WT1, b1,
          flag0, flagC, flagX);
  } else {
    roleB(bid - 3 * BB, n, smem, Xg, Wh1, out, flagC);
  }
}

// ---------------------------------------------------------------------------
extern "C" void kernel_launch(void* const* d_in, const int* in_sizes, int n_in,
                              void* d_out, int out_size, void* d_ws, size_t ws_size,
                              hipStream_t stream) {
  const float* x   = (const float*)d_in[0];
  const float* Wx0 = (const float*)d_in[1];
  const float* Wh0 = (const float*)d_in[2];
  const float* b0  = (const float*)d_in[3];
  const float* Wx1 = (const float*)d_in[4];
  const float* Wh1 = (const float*)d_in[5];
  const float* b1  = (const float*)d_in[6];
  float* out = (float*)d_out;

  // ws: Xg f16 [B*T][512] | hstream f16 [B*T][128] | WT0 | WT1 | flags x3
  char* base = (char*)d_ws;
  __half* Xg = (__half*)base;
  size_t off = (size_t)BB * TT * NG * sizeof(__half);      // 128 MB
  __half* hstream = (__half*)(base + off);
  off += (size_t)BB * TT * HH * sizeof(__half);            // +32 MB
  float* WT0 = (float*)(base + off);
  off += (size_t)II * NG * sizeof(float);
  float* WT1 = (float*)(base + off);
  off += (size_t)II * NG * sizeof(float);
  unsigned* flag0 = (unsigned*)(base + off);
  unsigned* flagC = flag0 + BB * NCH;
  unsigned* flagX = flagC + BB * NCH;

  hipFuncSetAttribute((const void*)lstm_mega,
                      hipFuncAttributeMaxDynamicSharedMemorySize, DYN_LDS);

  hipMemsetAsync(flag0, 0, 3 * (size_t)BB * NCH * sizeof(unsigned), stream);
  w_transpose2<<<512, 256, 0, stream>>>(Wx0, WT0, Wx1, WT1);
  // Prologue: Xg0 for chunks 0..LEAD-1 (rows [b*TT, b*TT+LEAD*CH))
  xg_gemm_pro<<<dim3(BB * 8, NG / 64), 256, 0, stream>>>(x, WT0, b0, Xg);
  lstm_mega<<<4 * BB, 512, DYN_LDS, stream>>>(Xg, hstream, x, Wh0, Wh1, WT0,
                                              b0, WT1, b1, out, flag0, flagC,
                                              flagX);
}

// Round 17
// 1931.253 us; speedup vs baseline: 1.0433x; 1.0433x over previous
//
#include <hip/hip_runtime.h>
#include <hip/hip_fp16.h>

// Problem constants
#define BB 64
#define TT 2048
#define II 128
#define HH 128
#define NG 512   // 4*H
#define CH 64    // pipeline chunk (steps)
#define NCH (TT / CH)
#define LEAD 8   // A's chunk lead (prologue covers chunks 0..LEAD-1 = 512 steps)
#define DYN_LDS 81984  // > 160KiB/2 -> hardware places only ONE WG per CU

typedef _Float16 h2_t __attribute__((ext_vector_type(2)));

#if defined(__has_builtin)
#if __has_builtin(__builtin_amdgcn_fdot2)
#define HAVE_FDOT2 1
#endif
#endif

__device__ __forceinline__ float fdot2f(h2_t a, h2_t b, float c) {
#ifdef HAVE_FDOT2
  return __builtin_amdgcn_fdot2(a, b, c, false);
#else
  return c + (float)a[0] * (float)b[0] + (float)a[1] * (float)b[1];
#endif
}

__device__ __forceinline__ float fast_sigmoid(float x) {
  float t = __builtin_amdgcn_exp2f(-1.4426950408889634f * x);
  return __builtin_amdgcn_rcpf(1.0f + t);
}
__device__ __forceinline__ float act_gate(float x, bool tanh_sel) {
  float xx = tanh_sel ? 2.0f * x : x;
  float s = fast_sigmoid(xx);
  return tanh_sel ? 2.0f * s - 1.0f : s;
}
__device__ __forceinline__ float fast_tanh(float x) {
  return 2.0f * fast_sigmoid(2.0f * x) - 1.0f;
}

__device__ __forceinline__ float dpp_xor1(float x) {
  return __int_as_float(__builtin_amdgcn_update_dpp(0, __float_as_int(x), 0xB1, 0xF, 0xF, true));
}
__device__ __forceinline__ float dpp_xor2(float x) {
  return __int_as_float(__builtin_amdgcn_update_dpp(0, __float_as_int(x), 0x4E, 0xF, 0xF, true));
}
// lane ^ 4 exchange via ds_swizzle BitMode: offset = (4<<10) | 0x1F
__device__ __forceinline__ float swz_xor4(float x) {
  return __int_as_float(__builtin_amdgcn_ds_swizzle(__float_as_int(x), 0x101F));
}

// LDS-only barrier: lgkmcnt drain + s_barrier (no vmcnt drain).
__device__ __forceinline__ void bar_lds() {
  __builtin_amdgcn_fence(__ATOMIC_RELEASE, "workgroup", "local");
  __builtin_amdgcn_s_barrier();
  __builtin_amdgcn_fence(__ATOMIC_ACQUIRE, "workgroup", "local");
}

union LD4 {
  float4 f4;
  h2_t h[4];
};
union LDB {
  uint4 u4;
  h2_t h[4];
};

__device__ __forceinline__ unsigned aload(unsigned* p) { return atomicAdd(p, 0u); }

// ---------------------------------------------------------------------------
// Transpose both Wx0 and Wx1: [512][128] -> [128][512]
// ---------------------------------------------------------------------------
__global__ void w_transpose2(const float* __restrict__ W0, float* __restrict__ T0,
                             const float* __restrict__ W1, float* __restrict__ T1) {
  int bid = blockIdx.x;
  const float* W = (bid < 256) ? W0 : W1;
  float* T = (bid < 256) ? T0 : T1;
  int idx = (bid & 255) * 256 + threadIdx.x;
  int n = idx >> 7;
  int k = idx & 127;
  T[k * NG + n] = W[idx];
}

// ---------------------------------------------------------------------------
// Prologue GEMM: Xg0 for chunks 0..LEAD-1 (rows [b*TT, b*TT+LEAD*CH)).
// grid.x = BB*8 (8 row-blocks of 64 = 512 rows/batch), grid.y = 8.
// ---------------------------------------------------------------------------
__global__ __launch_bounds__(256) void xg_gemm_pro(const float* __restrict__ X,
                                                   const float* __restrict__ WT,
                                                   const float* __restrict__ bias,
                                                   __half* __restrict__ Xg) {
  __shared__ float As[64][132];
  __shared__ float Bs[128][64];
  const int bx = blockIdx.x;
  const size_t m0 = (size_t)(bx >> 3) * TT + (bx & 7) * 64;
  const int n0 = blockIdx.y * 64;
  const int tid = threadIdx.x;

  {
    const float4* xv = (const float4*)(X + m0 * II);
#pragma unroll
    for (int r = 0; r < 8; ++r) {
      int f = tid + 256 * r;
      int m = f >> 5;
      int c4 = f & 31;
      float4 v = xv[m * 32 + c4];
      *(float4*)&As[m][c4 * 4] = v;
    }
  }
  {
#pragma unroll
    for (int r = 0; r < 8; ++r) {
      int f = tid + 256 * r;
      int k = f >> 4;
      int q = f & 15;
      float4 v = *(const float4*)(WT + (size_t)k * NG + n0 + q * 4);
      *(float4*)&Bs[k][q * 4] = v;
    }
  }
  __syncthreads();

  const int tx = tid & 15;
  const int ty = tid >> 4;
  float acc[4][4];
#pragma unroll
  for (int i = 0; i < 4; ++i)
#pragma unroll
    for (int j = 0; j < 4; ++j) acc[i][j] = 0.0f;

#pragma unroll 4
  for (int k = 0; k < 128; ++k) {
    float a0 = As[ty * 4 + 0][k];
    float a1 = As[ty * 4 + 1][k];
    float a2 = As[ty * 4 + 2][k];
    float a3 = As[ty * 4 + 3][k];
    float4 bv = *(const float4*)&Bs[k][tx * 4];
    acc[0][0] = fmaf(a0, bv.x, acc[0][0]);
    acc[0][1] = fmaf(a0, bv.y, acc[0][1]);
    acc[0][2] = fmaf(a0, bv.z, acc[0][2]);
    acc[0][3] = fmaf(a0, bv.w, acc[0][3]);
    acc[1][0] = fmaf(a1, bv.x, acc[1][0]);
    acc[1][1] = fmaf(a1, bv.y, acc[1][1]);
    acc[1][2] = fmaf(a1, bv.z, acc[1][2]);
    acc[1][3] = fmaf(a1, bv.w, acc[1][3]);
    acc[2][0] = fmaf(a2, bv.x, acc[2][0]);
    acc[2][1] = fmaf(a2, bv.y, acc[2][1]);
    acc[2][2] = fmaf(a2, bv.z, acc[2][2]);
    acc[2][3] = fmaf(a2, bv.w, acc[2][3]);
    acc[3][0] = fmaf(a3, bv.x, acc[3][0]);
    acc[3][1] = fmaf(a3, bv.y, acc[3][1]);
    acc[3][2] = fmaf(a3, bv.z, acc[3][2]);
    acc[3][3] = fmaf(a3, bv.w, acc[3][3]);
  }

  float4 bvec = *(const float4*)(bias + n0 + tx * 4);
#pragma unroll
  for (int i = 0; i < 4; ++i) {
    size_t m = m0 + ty * 4 + i;
    __half2* dst = (__half2*)(Xg + m * NG + n0 + tx * 4);
    dst[0] = __halves2half2(__float2half(acc[i][0] + bvec.x),
                            __float2half(acc[i][1] + bvec.y));
    dst[1] = __halves2half2(__float2half(acc[i][2] + bvec.z),
                            __float2half(acc[i][3] + bvec.w));
  }
}

// ===========================================================================
// Mega kernel: 256 WGs x 1024 threads, ONE WG per CU.
//   [0,64):    role A — L0 recurrence (16 waves: 4/SIMD for latency hiding)
//   [64,192):  role C — 2 WGs/batch, parity-assigned full chunks:
//              Xg0(cc+LEAD) -> flagX, wait flag0(cc) -> Xg1(cc) -> flagC
//              (compute guarded to n<512; barriers uniform)
//   [192,256): role B — L1 recurrence on Xg1 chunks
// Recurrence thread n: unit j=n>>3, K-eighth p=n&7, gate (p&3). 32 dot2 per
// thread; 8-lane reduce = quad DPP reduce-scatter + one ds_swizzle xor4.
// ===========================================================================

template <int LAYER>
__device__ __forceinline__ void role_rec(int b, int n, char* smem,
    const __half* Xg, const float* __restrict__ Wh,
    float* __restrict__ out, __half* hstream,
    unsigned* flagIn)   // LAYER 0: flagX (wait cc>=LEAD); LAYER 1: flagC
{
  const int j = n >> 3;        // unit 0..127
  const int p = n & 7;         // K-eighth; gate = p&3
  const int g0v_ = p & 3;
  const bool tsel = (g0v_ == 2);

  // weights: rows {g*128+j}, K-slice [16p, 16p+16) -> 8 h2 regs per gate row
  h2_t wh[4][8];
#pragma unroll
  for (int g = 0; g < 4; ++g) {
    const float2* ph = (const float2*)(Wh + (size_t)(g * 128 + j) * HH + p * 16);
#pragma unroll
    for (int k = 0; k < 8; ++k) {
      float2 v = ph[k];
      wh[g][k][0] = (_Float16)v.x;
      wh[g][k][1] = (_Float16)v.y;
    }
  }

  _Float16(*hb)[HH] = (_Float16(*)[HH])smem;
  if (n < HH) {
    hb[0][n] = (_Float16)0.0f;
    hb[1][n] = (_Float16)0.0f;
  }
  float c = 0.0f, hv = 0.0f;
  __syncthreads();

  // xg stream: this lane's gate row
  const __half* xs = Xg + (size_t)b * TT * NG + g0v_ * 128 + j;
  float* hT = out + (size_t)BB * TT * HH;
  float* cT = hT + 2 * BB * HH;
  __half* hsp = hstream + (size_t)b * TT * HH + j;
  float* outp = out + (size_t)b * TT * HH;

#pragma unroll 1
  for (int cc = 0; cc < NCH; ++cc) {
    if (LAYER == 0 ? (cc >= LEAD) : true) {
      if (n == 0) {
        while (aload(flagIn + b * NCH + cc) < 1u) __builtin_amdgcn_s_sleep(4);
      }
      __syncthreads();
      __builtin_amdgcn_fence(__ATOMIC_ACQUIRE, "agent");
    }
    __half xg_c = xs[(size_t)(cc * CH) * NG];

#pragma unroll 1
    for (int s = 0; s < CH; ++s) {
      const int i = cc * CH + s;
      __half xg_n = (s + 1 < CH) ? xs[(size_t)(i + 1) * NG] : __float2half(0.0f);

      // ---- 32 dot2: partials of the 4 gate rows over K-slice [16p,16p+16) --
      const char* H = (const char*)hb[i & 1] + p * 32;
      LD4 u0, u1;
      u0.f4 = *(const float4*)(H);
      u1.f4 = *(const float4*)(H + 16);
      float a0 = 0.f, a1 = 0.f, a2 = 0.f, a3 = 0.f;
#pragma unroll
      for (int t = 0; t < 4; ++t) {
        a0 = fdot2f(wh[0][t], u0.h[t], a0);
        a1 = fdot2f(wh[1][t], u0.h[t], a1);
        a2 = fdot2f(wh[2][t], u0.h[t], a2);
        a3 = fdot2f(wh[3][t], u0.h[t], a3);
      }
#pragma unroll
      for (int t = 0; t < 4; ++t) {
        a0 = fdot2f(wh[0][4 + t], u1.h[t], a0);
        a1 = fdot2f(wh[1][4 + t], u1.h[t], a1);
        a2 = fdot2f(wh[2][4 + t], u1.h[t], a2);
        a3 = fdot2f(wh[3][4 + t], u1.h[t], a3);
      }

      // ---- quad reduce-scatter (lane p&3 <- gate p&3, quad-local sum) ----
      float k01 = (p & 1) ? a1 : a0;
      float u01 = (p & 1) ? a0 : a1;
      float r01 = k01 + dpp_xor1(u01);
      float k23 = (p & 1) ? a3 : a2;
      float u23 = (p & 1) ? a2 : a3;
      float r23 = k23 + dpp_xor1(u23);
      float kA = (p & 2) ? r23 : r01;
      float uA = (p & 2) ? r01 : r23;
      float sLq = kA + dpp_xor2(uA);
      // ---- combine the two quads (K-halves): lane^4 exchange ----
      float sL = sLq + swz_xor4(sLq);

      float aL = act_gate(sL + __half2float(xg_c), tsel);
      float fg = dpp_xor1(aL);
      float gg = dpp_xor2(aL);
      float og = dpp_xor2(fg);
      if (p == 0) {
        c = fg * c + aL * gg;
        hv = og * fast_tanh(c);
        _Float16 hf = (_Float16)hv;
        hb[(i & 1) ^ 1][j] = hf;
        if (LAYER == 0) {
          *(_Float16*)(hsp + (size_t)i * HH) = hf;
        } else {
          outp[(size_t)i * HH + j] = hv;
        }
      }
      bar_lds();
      xg_c = xg_n;
    }
    if (LAYER == 0) {
      __syncthreads();   // drains hstream stores (vmcnt)
      if (n == 0) {
        __builtin_amdgcn_fence(__ATOMIC_RELEASE, "agent");
        atomicExch(out ? (unsigned*)0 : (unsigned*)0, 0u);  // never taken
      }
    }
    if (LAYER == 0 && n == 0) {
      __builtin_amdgcn_fence(__ATOMIC_RELEASE, "agent");
    }
    if (LAYER == 0) {
      if (n == 0) atomicExch((unsigned*)flagIn - (size_t)BB * NCH + b * NCH + cc, 1u);
      // NOTE: flag0 array sits immediately BEFORE flagX in ws; see launch.
    }
  }

  if (p == 0) {
    hT[LAYER * BB * HH + b * HH + j] = hv;
    cT[LAYER * BB * HH + b * HH + j] = c;
  }
}

// ---- role C: parity-assigned chunks; Xg0(cc+LEAD) then Xg1(cc) ----
__device__ __forceinline__ void roleC(int cidx, int n, char* smem,
    __half* Xg, const __half* hstream, const float* __restrict__ x,
    const float* __restrict__ WT0, const float* __restrict__ b0,
    const float* __restrict__ WT1, const float* __restrict__ b1,
    unsigned* flag0, unsigned* flagC, unsigned* flagX)
{
  const int b = cidx >> 1;
  const int par = cidx & 1;
  h2_t(*As2)[68] = (h2_t(*)[68])smem;                    // [64][68] h2
  h2_t(*Bs2)[64] = (h2_t(*)[64])(smem + 64 * 68 * 4);    // [64][64] h2

  const int ty = n >> 4;   // 0..31 (n<512)
  const int tx = n & 15;
  const int mf = n >> 3;   // 0..63  (n<512)
  const int sf = n & 7;

#pragma unroll 1
  for (int cc = par; cc < NCH; cc += 2) {
    // ======== part X0: Xg0 for chunk cc+LEAD (input-only, no waits) ========
    if (cc + LEAD < NCH) {
      const int t0x = (cc + LEAD) * CH;
      if (n < 512) {
        const float4* sx = (const float4*)(x + ((size_t)b * TT + t0x + mf) * II + sf * 16);
        float4 p0 = sx[0], p1 = sx[1], p2 = sx[2], p3 = sx[3];
        h2_t r[8];
        r[0][0] = (_Float16)p0.x; r[0][1] = (_Float16)p0.y;
        r[1][0] = (_Float16)p0.z; r[1][1] = (_Float16)p0.w;
        r[2][0] = (_Float16)p1.x; r[2][1] = (_Float16)p1.y;
        r[3][0] = (_Float16)p1.z; r[3][1] = (_Float16)p1.w;
        r[4][0] = (_Float16)p2.x; r[4][1] = (_Float16)p2.y;
        r[5][0] = (_Float16)p2.z; r[5][1] = (_Float16)p2.w;
        r[6][0] = (_Float16)p3.x; r[6][1] = (_Float16)p3.y;
        r[7][0] = (_Float16)p3.z; r[7][1] = (_Float16)p3.w;
        *(uint4*)&As2[mf][sf * 8] = *(uint4*)&r[0];
        *(uint4*)&As2[mf][sf * 8 + 4] = *(uint4*)&r[4];
      }
#pragma unroll 1
      for (int nt = 0; nt < 8; ++nt) {
        __syncthreads();
        if (n < 512) {
          const int kp = n >> 3, cg = n & 7;
          const float4* w0 = (const float4*)(WT0 + (size_t)(2 * kp) * NG + nt * 64 + cg * 8);
          const float4* w1 = (const float4*)(WT0 + (size_t)(2 * kp + 1) * NG + nt * 64 + cg * 8);
          float4 x0 = w0[0], x1 = w0[1];
          float4 y0 = w1[0], y1 = w1[1];
          h2_t r[8];
          r[0][0] = (_Float16)x0.x; r[0][1] = (_Float16)y0.x;
          r[1][0] = (_Float16)x0.y; r[1][1] = (_Float16)y0.y;
          r[2][0] = (_Float16)x0.z; r[2][1] = (_Float16)y0.z;
          r[3][0] = (_Float16)x0.w; r[3][1] = (_Float16)y0.w;
          r[4][0] = (_Float16)x1.x; r[4][1] = (_Float16)y1.x;
          r[5][0] = (_Float16)x1.y; r[5][1] = (_Float16)y1.y;
          r[6][0] = (_Float16)x1.z; r[6][1] = (_Float16)y1.z;
          r[7][0] = (_Float16)x1.w; r[7][1] = (_Float16)y1.w;
          *(uint4*)&Bs2[kp][cg * 8] = *(uint4*)&r[0];
          *(uint4*)&Bs2[kp][cg * 8 + 4] = *(uint4*)&r[4];
        }
        __syncthreads();

        if (n < 512) {
          float acc[2][4];
#pragma unroll
          for (int r = 0; r < 2; ++r)
#pragma unroll
            for (int q = 0; q < 4; ++q) acc[r][q] = 0.0f;
#pragma unroll 4
          for (int k4 = 0; k4 < 16; ++k4) {
            LDB ua0, ua1;
            ua0.u4 = *(const uint4*)&As2[ty * 2][k4 * 4];
            ua1.u4 = *(const uint4*)&As2[ty * 2 + 1][k4 * 4];
#pragma unroll
            for (int t = 0; t < 4; ++t) {
              LDB ub;
              ub.u4 = *(const uint4*)&Bs2[k4 * 4 + t][tx * 4];
              acc[0][0] = fdot2f(ua0.h[t], ub.h[0], acc[0][0]);
              acc[0][1] = fdot2f(ua0.h[t], ub.h[1], acc[0][1]);
              acc[0][2] = fdot2f(ua0.h[t], ub.h[2], acc[0][2]);
              acc[0][3] = fdot2f(ua0.h[t], ub.h[3], acc[0][3]);
              acc[1][0] = fdot2f(ua1.h[t], ub.h[0], acc[1][0]);
              acc[1][1] = fdot2f(ua1.h[t], ub.h[1], acc[1][1]);
              acc[1][2] = fdot2f(ua1.h[t], ub.h[2], acc[1][2]);
              acc[1][3] = fdot2f(ua1.h[t], ub.h[3], acc[1][3]);
            }
          }
          const int col = nt * 64 + tx * 4;
          float4 bv = *(const float4*)(b0 + col);
#pragma unroll
          for (int r = 0; r < 2; ++r) {
            __half2* d = (__half2*)(Xg + ((size_t)b * TT + t0x + ty * 2 + r) * NG + col);
            d[0] = __halves2half2(__float2half(acc[r][0] + bv.x),
                                  __float2half(acc[r][1] + bv.y));
            d[1] = __halves2half2(__float2half(acc[r][2] + bv.z),
                                  __float2half(acc[r][3] + bv.w));
          }
        }
      }
      __syncthreads();   // drain Xg0 stores + protect As2
      if (n == 0) {
        __builtin_amdgcn_fence(__ATOMIC_RELEASE, "agent");
        atomicExch(flagX + b * NCH + cc + LEAD, 1u);
      }
    }

    // ======== part X1: Xg1 for chunk cc (waits on h0) ========
    if (n == 0) {
      while (aload(flag0 + b * NCH + cc) < 1u) __builtin_amdgcn_s_sleep(8);
    }
    __syncthreads();
    __builtin_amdgcn_fence(__ATOMIC_ACQUIRE, "agent");

    const int t0 = cc * CH;
    if (n < 512) {
      const uint4* src = (const uint4*)(hstream + ((size_t)b * TT + t0 + mf) * HH + sf * 16);
      uint4 v0 = src[0], v1 = src[1];
      *(uint4*)&As2[mf][sf * 8] = v0;
      *(uint4*)&As2[mf][sf * 8 + 4] = v1;
    }
#pragma unroll 1
    for (int nt = 0; nt < 8; ++nt) {
      __syncthreads();
      if (n < 512) {
        const int kp = n >> 3, cg = n & 7;
        const float4* w0 = (const float4*)(WT1 + (size_t)(2 * kp) * NG + nt * 64 + cg * 8);
        const float4* w1 = (const float4*)(WT1 + (size_t)(2 * kp + 1) * NG + nt * 64 + cg * 8);
        float4 x0 = w0[0], x1 = w0[1];
        float4 y0 = w1[0], y1 = w1[1];
        h2_t r[8];
        r[0][0] = (_Float16)x0.x; r[0][1] = (_Float16)y0.x;
        r[1][0] = (_Float16)x0.y; r[1][1] = (_Float16)y0.y;
        r[2][0] = (_Float16)x0.z; r[2][1] = (_Float16)y0.z;
        r[3][0] = (_Float16)x0.w; r[3][1] = (_Float16)y0.w;
        r[4][0] = (_Float16)x1.x; r[4][1] = (_Float16)y1.x;
        r[5][0] = (_Float16)x1.y; r[5][1] = (_Float16)y1.y;
        r[6][0] = (_Float16)x1.z; r[6][1] = (_Float16)y1.z;
        r[7][0] = (_Float16)x1.w; r[7][1] = (_Float16)y1.w;
        *(uint4*)&Bs2[kp][cg * 8] = *(uint4*)&r[0];
        *(uint4*)&Bs2[kp][cg * 8 + 4] = *(uint4*)&r[4];
      }
      __syncthreads();

      if (n < 512) {
        float acc[2][4];
#pragma unroll
        for (int r = 0; r < 2; ++r)
#pragma unroll
          for (int q = 0; q < 4; ++q) acc[r][q] = 0.0f;
#pragma unroll 4
        for (int k4 = 0; k4 < 16; ++k4) {
          LDB ua0, ua1;
          ua0.u4 = *(const uint4*)&As2[ty * 2][k4 * 4];
          ua1.u4 = *(const uint4*)&As2[ty * 2 + 1][k4 * 4];
#pragma unroll
          for (int t = 0; t < 4; ++t) {
            LDB ub;
            ub.u4 = *(const uint4*)&Bs2[k4 * 4 + t][tx * 4];
            acc[0][0] = fdot2f(ua0.h[t], ub.h[0], acc[0][0]);
            acc[0][1] = fdot2f(ua0.h[t], ub.h[1], acc[0][1]);
            acc[0][2] = fdot2f(ua0.h[t], ub.h[2], acc[0][2]);
            acc[0][3] = fdot2f(ua0.h[t], ub.h[3], acc[0][3]);
            acc[1][0] = fdot2f(ua1.h[t], ub.h[0], acc[1][0]);
            acc[1][1] = fdot2f(ua1.h[t], ub.h[1], acc[1][1]);
            acc[1][2] = fdot2f(ua1.h[t], ub.h[2], acc[1][2]);
            acc[1][3] = fdot2f(ua1.h[t], ub.h[3], acc[1][3]);
          }
        }
        const int col = nt * 64 + tx * 4;
        float4 bv = *(const float4*)(b1 + col);
#pragma unroll
        for (int r = 0; r < 2; ++r) {
          __half2* d = (__half2*)(Xg + ((size_t)b * TT + t0 + ty * 2 + r) * NG + col);
          d[0] = __halves2half2(__float2half(acc[r][0] + bv.x),
                                __float2half(acc[r][1] + bv.y));
          d[1] = __halves2half2(__float2half(acc[r][2] + bv.z),
                                __float2half(acc[r][3] + bv.w));
        }
      }
    }
    __syncthreads();
    if (n == 0) {
      __builtin_amdgcn_fence(__ATOMIC_RELEASE, "agent");
      atomicExch(flagC + b * NCH + cc, 1u);
    }
  }
}

// ---- recurrence wrapper with explicit flag pointers (A publishes flag0) ----
template <int LAYER>
__device__ __forceinline__ void role_rec2(int b, int n, char* smem,
    const __half* Xg, const float* __restrict__ Wh,
    float* __restrict__ out, __half* hstream,
    unsigned* flagWait, unsigned* flagPub)
{
  const int j = n >> 3;
  const int p = n & 7;
  const int gate = p & 3;
  const bool tsel = (gate == 2);

  h2_t wh[4][8];
#pragma unroll
  for (int g = 0; g < 4; ++g) {
    const float2* ph = (const float2*)(Wh + (size_t)(g * 128 + j) * HH + p * 16);
#pragma unroll
    for (int k = 0; k < 8; ++k) {
      float2 v = ph[k];
      wh[g][k][0] = (_Float16)v.x;
      wh[g][k][1] = (_Float16)v.y;
    }
  }

  _Float16(*hb)[HH] = (_Float16(*)[HH])smem;
  if (n < HH) {
    hb[0][n] = (_Float16)0.0f;
    hb[1][n] = (_Float16)0.0f;
  }
  float c = 0.0f, hv = 0.0f;
  __syncthreads();

  const __half* xs = Xg + (size_t)b * TT * NG + gate * 128 + j;
  float* hT = out + (size_t)BB * TT * HH;
  float* cT = hT + 2 * BB * HH;
  __half* hsp = hstream + (size_t)b * TT * HH + j;
  float* outp = out + (size_t)b * TT * HH;

#pragma unroll 1
  for (int cc = 0; cc < NCH; ++cc) {
    const bool needWait = (LAYER == 0) ? (cc >= LEAD) : true;
    if (needWait) {
      if (n == 0) {
        while (aload(flagWait + b * NCH + cc) < 1u) __builtin_amdgcn_s_sleep(4);
      }
      __syncthreads();
      __builtin_amdgcn_fence(__ATOMIC_ACQUIRE, "agent");
    }
    __half xg_c = xs[(size_t)(cc * CH) * NG];

#pragma unroll 1
    for (int s = 0; s < CH; ++s) {
      const int i = cc * CH + s;
      __half xg_n = (s + 1 < CH) ? xs[(size_t)(i + 1) * NG] : __float2half(0.0f);

      const char* H = (const char*)hb[i & 1] + p * 32;
      LD4 u0, u1;
      u0.f4 = *(const float4*)(H);
      u1.f4 = *(const float4*)(H + 16);
      float a0 = 0.f, a1 = 0.f, a2 = 0.f, a3 = 0.f;
#pragma unroll
      for (int t = 0; t < 4; ++t) {
        a0 = fdot2f(wh[0][t], u0.h[t], a0);
        a1 = fdot2f(wh[1][t], u0.h[t], a1);
        a2 = fdot2f(wh[2][t], u0.h[t], a2);
        a3 = fdot2f(wh[3][t], u0.h[t], a3);
      }
#pragma unroll
      for (int t = 0; t < 4; ++t) {
        a0 = fdot2f(wh[0][4 + t], u1.h[t], a0);
        a1 = fdot2f(wh[1][4 + t], u1.h[t], a1);
        a2 = fdot2f(wh[2][4 + t], u1.h[t], a2);
        a3 = fdot2f(wh[3][4 + t], u1.h[t], a3);
      }

      float k01 = (p & 1) ? a1 : a0;
      float u01 = (p & 1) ? a0 : a1;
      float r01 = k01 + dpp_xor1(u01);
      float k23 = (p & 1) ? a3 : a2;
      float u23 = (p & 1) ? a2 : a3;
      float r23 = k23 + dpp_xor1(u23);
      float kA = (p & 2) ? r23 : r01;
      float uA = (p & 2) ? r01 : r23;
      float sLq = kA + dpp_xor2(uA);
      float sL = sLq + swz_xor4(sLq);

      float aL = act_gate(sL + __half2float(xg_c), tsel);
      float fg = dpp_xor1(aL);
      float gg = dpp_xor2(aL);
      float og = dpp_xor2(fg);
      if (p == 0) {
        c = fg * c + aL * gg;
        hv = og * fast_tanh(c);
        _Float16 hf = (_Float16)hv;
        hb[(i & 1) ^ 1][j] = hf;
        if (LAYER == 0) {
          *(_Float16*)(hsp + (size_t)i * HH) = hf;
        } else {
          outp[(size_t)i * HH + j] = hv;
        }
      }
      bar_lds();
      xg_c = xg_n;
    }
    if (LAYER == 0) {
      __syncthreads();   // drains hstream stores (vmcnt)
      if (n == 0) {
        __builtin_amdgcn_fence(__ATOMIC_RELEASE, "agent");
        atomicExch(flagPub + b * NCH + cc, 1u);
      }
    }
  }

  if (p == 0) {
    hT[LAYER * BB * HH + b * HH + j] = hv;
    cT[LAYER * BB * HH + b * HH + j] = c;
  }
}

__global__
__attribute__((amdgpu_flat_work_group_size(1024, 1024)))
void lstm_mega(__half* Xg, __half* hstream, const float* __restrict__ x,
               const float* __restrict__ Wh0,
               const float* __restrict__ Wh1,
               const float* __restrict__ WT0,
               const float* __restrict__ b0,
               const float* __restrict__ WT1,
               const float* __restrict__ b1,
               float* __restrict__ out,
               unsigned* flag0, unsigned* flagC, unsigned* flagX)
{
  extern __shared__ __align__(16) char smem[];   // DYN_LDS bytes: 1 WG/CU
  const int bid = blockIdx.x;
  const int n = threadIdx.x;
  if (bid < BB) {
    role_rec2<0>(bid, n, smem, Xg, Wh0, out, hstream, flagX, flag0);
  } else if (bid < BB + 2 * BB) {
    roleC(bid - BB, n, smem, Xg, hstream, x, WT0, b0, WT1, b1,
          flag0, flagC, flagX);
  } else {
    role_rec2<1>(bid - 3 * BB, n, smem, Xg, Wh1, out, hstream, flagC, flag0);
  }
}

// ---------------------------------------------------------------------------
extern "C" void kernel_launch(void* const* d_in, const int* in_sizes, int n_in,
                              void* d_out, int out_size, void* d_ws, size_t ws_size,
                              hipStream_t stream) {
  const float* x   = (const float*)d_in[0];
  const float* Wx0 = (const float*)d_in[1];
  const float* Wh0 = (const float*)d_in[2];
  const float* b0  = (const float*)d_in[3];
  const float* Wx1 = (const float*)d_in[4];
  const float* Wh1 = (const float*)d_in[5];
  const float* b1  = (const float*)d_in[6];
  float* out = (float*)d_out;

  // ws: Xg f16 [B*T][512] | hstream f16 [B*T][128] | WT0 | WT1 | flags x3
  char* base = (char*)d_ws;
  __half* Xg = (__half*)base;
  size_t off = (size_t)BB * TT * NG * sizeof(__half);      // 128 MB
  __half* hstream = (__half*)(base + off);
  off += (size_t)BB * TT * HH * sizeof(__half);            // +32 MB
  float* WT0 = (float*)(base + off);
  off += (size_t)II * NG * sizeof(float);
  float* WT1 = (float*)(base + off);
  off += (size_t)II * NG * sizeof(float);
  unsigned* flag0 = (unsigned*)(base + off);
  unsigned* flagC = flag0 + BB * NCH;
  unsigned* flagX = flagC + BB * NCH;

  hipFuncSetAttribute((const void*)lstm_mega,
                      hipFuncAttributeMaxDynamicSharedMemorySize, DYN_LDS);

  hipMemsetAsync(flag0, 0, 3 * (size_t)BB * NCH * sizeof(unsigned), stream);
  w_transpose2<<<512, 256, 0, stream>>>(Wx0, WT0, Wx1, WT1);
  // Prologue: Xg0 for chunks 0..LEAD-1 (rows [b*TT, b*TT+512))
  xg_gemm_pro<<<dim3(BB * 8, NG / 64), 256, 0, stream>>>(x, WT0, b0, Xg);
  lstm_mega<<<4 * BB, 1024, DYN_LDS, stream>>>(Xg, hstream, x, Wh0, Wh1, WT0,
                                               b0, WT1, b1, out, flag0, flagC,
                                               flagX);
}

// Round 18
// 1854.472 us; speedup vs baseline: 1.0865x; 1.0414x over previous
//
#include <hip/hip_runtime.h>
#include <hip/hip_fp16.h>

// Problem constants
#define BB 64
#define TT 2048
#define II 128
#define HH 128
#define NG 512   // 4*H
#define CH 128   // pipeline chunk (steps)
#define NCH (TT / CH)
#define LEAD 4   // A's chunk lead (prologue covers chunks 0..LEAD-1)
#define DYN_LDS 81984  // > 160KiB/2 -> hardware places only ONE WG per CU

typedef _Float16 h2_t __attribute__((ext_vector_type(2)));

#if defined(__has_builtin)
#if __has_builtin(__builtin_amdgcn_fdot2)
#define HAVE_FDOT2 1
#endif
#endif

__device__ __forceinline__ float fdot2f(h2_t a, h2_t b, float c) {
#ifdef HAVE_FDOT2
  return __builtin_amdgcn_fdot2(a, b, c, false);
#else
  return c + (float)a[0] * (float)b[0] + (float)a[1] * (float)b[1];
#endif
}

__device__ __forceinline__ float fast_sigmoid(float x) {
  float t = __builtin_amdgcn_exp2f(-1.4426950408889634f * x);
  return __builtin_amdgcn_rcpf(1.0f + t);
}
__device__ __forceinline__ float act_gate(float x, bool tanh_sel) {
  float xx = tanh_sel ? 2.0f * x : x;
  float s = fast_sigmoid(xx);
  return tanh_sel ? 2.0f * s - 1.0f : s;
}
__device__ __forceinline__ float fast_tanh(float x) {
  return 2.0f * fast_sigmoid(2.0f * x) - 1.0f;
}

__device__ __forceinline__ float dpp_xor1(float x) {
  return __int_as_float(__builtin_amdgcn_update_dpp(0, __float_as_int(x), 0xB1, 0xF, 0xF, true));
}
__device__ __forceinline__ float dpp_xor2(float x) {
  return __int_as_float(__builtin_amdgcn_update_dpp(0, __float_as_int(x), 0x4E, 0xF, 0xF, true));
}

// LDS-only barrier: lgkmcnt drain + s_barrier (no vmcnt drain).
__device__ __forceinline__ void bar_lds() {
  __builtin_amdgcn_fence(__ATOMIC_RELEASE, "workgroup", "local");
  __builtin_amdgcn_s_barrier();
  __builtin_amdgcn_fence(__ATOMIC_ACQUIRE, "workgroup", "local");
}

union LDB {
  uint4 u4;
  h2_t h[4];
};

__device__ __forceinline__ unsigned aload(unsigned* p) { return atomicAdd(p, 0u); }

// ---------------------------------------------------------------------------
// Transpose both Wx0 and Wx1: [512][128] -> [128][512]
// ---------------------------------------------------------------------------
__global__ void w_transpose2(const float* __restrict__ W0, float* __restrict__ T0,
                             const float* __restrict__ W1, float* __restrict__ T1) {
  int bid = blockIdx.x;
  const float* W = (bid < 256) ? W0 : W1;
  float* T = (bid < 256) ? T0 : T1;
  int idx = (bid & 255) * 256 + threadIdx.x;
  int n = idx >> 7;
  int k = idx & 127;
  T[k * NG + n] = W[idx];
}

// ---------------------------------------------------------------------------
// Prologue GEMM: Xg0 for chunks 0..LEAD-1 (rows [b*TT, b*TT+LEAD*CH)).
// ---------------------------------------------------------------------------
__global__ __launch_bounds__(256) void xg_gemm_pro(const float* __restrict__ X,
                                                   const float* __restrict__ WT,
                                                   const float* __restrict__ bias,
                                                   __half* __restrict__ Xg) {
  __shared__ float As[64][132];
  __shared__ float Bs[128][64];
  const int bx = blockIdx.x;
  const size_t m0 = (size_t)(bx >> 3) * TT + (bx & 7) * 64;
  const int n0 = blockIdx.y * 64;
  const int tid = threadIdx.x;

  {
    const float4* xv = (const float4*)(X + m0 * II);
#pragma unroll
    for (int r = 0; r < 8; ++r) {
      int f = tid + 256 * r;
      int m = f >> 5;
      int c4 = f & 31;
      float4 v = xv[m * 32 + c4];
      *(float4*)&As[m][c4 * 4] = v;
    }
  }
  {
#pragma unroll
    for (int r = 0; r < 8; ++r) {
      int f = tid + 256 * r;
      int k = f >> 4;
      int q = f & 15;
      float4 v = *(const float4*)(WT + (size_t)k * NG + n0 + q * 4);
      *(float4*)&Bs[k][q * 4] = v;
    }
  }
  __syncthreads();

  const int tx = tid & 15;
  const int ty = tid >> 4;
  float acc[4][4];
#pragma unroll
  for (int i = 0; i < 4; ++i)
#pragma unroll
    for (int j = 0; j < 4; ++j) acc[i][j] = 0.0f;

#pragma unroll 4
  for (int k = 0; k < 128; ++k) {
    float a0 = As[ty * 4 + 0][k];
    float a1 = As[ty * 4 + 1][k];
    float a2 = As[ty * 4 + 2][k];
    float a3 = As[ty * 4 + 3][k];
    float4 bv = *(const float4*)&Bs[k][tx * 4];
    acc[0][0] = fmaf(a0, bv.x, acc[0][0]);
    acc[0][1] = fmaf(a0, bv.y, acc[0][1]);
    acc[0][2] = fmaf(a0, bv.z, acc[0][2]);
    acc[0][3] = fmaf(a0, bv.w, acc[0][3]);
    acc[1][0] = fmaf(a1, bv.x, acc[1][0]);
    acc[1][1] = fmaf(a1, bv.y, acc[1][1]);
    acc[1][2] = fmaf(a1, bv.z, acc[1][2]);
    acc[1][3] = fmaf(a1, bv.w, acc[1][3]);
    acc[2][0] = fmaf(a2, bv.x, acc[2][0]);
    acc[2][1] = fmaf(a2, bv.y, acc[2][1]);
    acc[2][2] = fmaf(a2, bv.z, acc[2][2]);
    acc[2][3] = fmaf(a2, bv.w, acc[2][3]);
    acc[3][0] = fmaf(a3, bv.x, acc[3][0]);
    acc[3][1] = fmaf(a3, bv.y, acc[3][1]);
    acc[3][2] = fmaf(a3, bv.z, acc[3][2]);
    acc[3][3] = fmaf(a3, bv.w, acc[3][3]);
  }

  float4 bvec = *(const float4*)(bias + n0 + tx * 4);
#pragma unroll
  for (int i = 0; i < 4; ++i) {
    size_t m = m0 + ty * 4 + i;
    __half2* dst = (__half2*)(Xg + m * NG + n0 + tx * 4);
    dst[0] = __halves2half2(__float2half(acc[i][0] + bvec.x),
                            __float2half(acc[i][1] + bvec.y));
    dst[1] = __halves2half2(__float2half(acc[i][2] + bvec.z),
                            __float2half(acc[i][3] + bvec.w));
  }
}

// ===========================================================================
// Mega kernel: 256 WGs, ONE per CU (dynamic LDS > 160KiB/2).
//   [0,64):    role A — L0 recurrence (waits flagX for cc>=LEAD), flag0/chunk
//   [64,192):  role C — per iter cc: Xg0(cc+LEAD) -> flagX, then wait
//              flag0(cc) -> Xg1(cc)=h0@Wx1^T+b1 (in place) -> flagC
//   [192,256): role B — L1 recurrence on Xg1 chunks (waits flagC>=2)
// Recurrence inner product: plain v_fma_f32 (HW-measured 2 cyc/inst =
// 2 cyc/MAC) instead of v_dot2_f32_f16 (~6 cyc/inst = 3 cyc/MAC).
// f32 weights in registers; h kept f32 in LDS (quad-broadcast reads).
// ===========================================================================

// ---- role A: layer-0 recurrence (f32 FMA inner product) ----
__device__ __forceinline__ void roleA(int b, int n, char* smem,
    const __half* Xg, const float* __restrict__ Wh0,
    float* __restrict__ out, __half* hstream,
    unsigned* flag0, unsigned* flagX)
{
  const int j = n >> 2;
  const int p = n & 3;
  const bool tsel = (p == 2);

  // f32 weights: rows {g*128+j}, K-slice [32p, 32p+32) -> 32 floats per row
  float wh[4][32];
#pragma unroll
  for (int g = 0; g < 4; ++g) {
    const float4* ph = (const float4*)(Wh0 + (size_t)(g * 128 + j) * HH + p * 32);
#pragma unroll
    for (int k = 0; k < 8; ++k) {
      float4 v = ph[k];
      wh[g][4 * k + 0] = v.x;
      wh[g][4 * k + 1] = v.y;
      wh[g][4 * k + 2] = v.z;
      wh[g][4 * k + 3] = v.w;
    }
  }

  float(*hb)[HH] = (float(*)[HH])smem;   // f32 h, double-buffered (1 KB)
  if (n < HH) {
    hb[0][n] = 0.0f;
    hb[1][n] = 0.0f;
  }
  float c = 0.0f, hv = 0.0f;
  __syncthreads();

  const __half* xs = Xg + (size_t)b * TT * NG + p * 128 + j;
  float* hT = out + (size_t)BB * TT * HH;
  float* cT = hT + 2 * BB * HH;
  __half* hsp = hstream + (size_t)b * TT * HH + j;

#pragma unroll 1
  for (int cc = 0; cc < NCH; ++cc) {
    if (cc >= LEAD) {
      if (n == 0) {
        while (aload(flagX + b * NCH + cc) < 2u) __builtin_amdgcn_s_sleep(1);
      }
      __syncthreads();
      __builtin_amdgcn_fence(__ATOMIC_ACQUIRE, "agent");
    }
    __half xg_c = xs[(size_t)(cc * CH) * NG];

#pragma unroll 1
    for (int s = 0; s < CH; ++s) {
      const int i = cc * CH + s;
      __half xg_n = (s + 1 < CH) ? xs[(size_t)(i + 1) * NG] : __float2half(0.0f);

      const float* H = hb[i & 1] + p * 32;
      float a0 = 0.f, a1 = 0.f, a2 = 0.f, a3 = 0.f;
#pragma unroll
      for (int q = 0; q < 8; ++q) {
        float4 u = *(const float4*)(H + q * 4);
        const int m = q * 4;
        a0 = fmaf(wh[0][m + 0], u.x, a0);
        a1 = fmaf(wh[1][m + 0], u.x, a1);
        a2 = fmaf(wh[2][m + 0], u.x, a2);
        a3 = fmaf(wh[3][m + 0], u.x, a3);
        a0 = fmaf(wh[0][m + 1], u.y, a0);
        a1 = fmaf(wh[1][m + 1], u.y, a1);
        a2 = fmaf(wh[2][m + 1], u.y, a2);
        a3 = fmaf(wh[3][m + 1], u.y, a3);
        a0 = fmaf(wh[0][m + 2], u.z, a0);
        a1 = fmaf(wh[1][m + 2], u.z, a1);
        a2 = fmaf(wh[2][m + 2], u.z, a2);
        a3 = fmaf(wh[3][m + 2], u.z, a3);
        a0 = fmaf(wh[0][m + 3], u.w, a0);
        a1 = fmaf(wh[1][m + 3], u.w, a1);
        a2 = fmaf(wh[2][m + 3], u.w, a2);
        a3 = fmaf(wh[3][m + 3], u.w, a3);
      }

      float k01 = (p & 1) ? a1 : a0;
      float u01 = (p & 1) ? a0 : a1;
      float r01 = k01 + dpp_xor1(u01);
      float k23 = (p & 1) ? a3 : a2;
      float u23 = (p & 1) ? a2 : a3;
      float r23 = k23 + dpp_xor1(u23);
      float kA = (p & 2) ? r23 : r01;
      float uA = (p & 2) ? r01 : r23;
      float sL = kA + dpp_xor2(uA);
      float aL = act_gate(sL + __half2float(xg_c), tsel);
      float fg = dpp_xor1(aL);
      float gg = dpp_xor2(aL);
      float og = dpp_xor2(fg);
      if (p == 0) {
        c = fg * c + aL * gg;
        hv = og * fast_tanh(c);
        hb[(i & 1) ^ 1][j] = hv;
        *(_Float16*)(hsp + (size_t)i * HH) = (_Float16)hv;
      }
      bar_lds();
      xg_c = xg_n;
    }
    __syncthreads();   // drains hstream stores (vmcnt)
    if (n == 0) {
      __builtin_amdgcn_fence(__ATOMIC_RELEASE, "agent");
      atomicExch(flag0 + b * NCH + cc, 1u);
    }
  }

  if (p == 0) {
    hT[b * HH + j] = hv;
    cT[b * HH + j] = c;
  }
}

// ---- role C: Xg0(cc+LEAD) production then Xg1(cc) bridge GEMM ----
__device__ __forceinline__ void roleC(int cidx, int n, char* smem,
    __half* Xg, const __half* hstream, const float* __restrict__ x,
    const float* __restrict__ WT0, const float* __restrict__ b0,
    const float* __restrict__ WT1, const float* __restrict__ b1,
    unsigned* flag0, unsigned* flagC, unsigned* flagX)
{
  const int b = cidx >> 1;
  const int half = cidx & 1;
  h2_t(*As2)[68] = (h2_t(*)[68])smem;                    // [64][68] h2
  h2_t(*Bs2)[64] = (h2_t(*)[64])(smem + 64 * 68 * 4);    // [64][64] h2

  const int ty = n >> 4;
  const int tx = n & 15;
  const int mf = n >> 3;   // fill row
  const int sf = n & 7;    // fill segment

#pragma unroll 1
  for (int cc = 0; cc < NCH; ++cc) {
    // ======== part X0: Xg0 for chunk cc+LEAD (input-only, no waits) ========
    if (cc + LEAD < NCH) {
      const int t0x = (cc + LEAD) * CH + half * 64;
      {
        const float4* sx = (const float4*)(x + ((size_t)b * TT + t0x + mf) * II + sf * 16);
        float4 p0 = sx[0], p1 = sx[1], p2 = sx[2], p3 = sx[3];
        h2_t r[8];
        r[0][0] = (_Float16)p0.x; r[0][1] = (_Float16)p0.y;
        r[1][0] = (_Float16)p0.z; r[1][1] = (_Float16)p0.w;
        r[2][0] = (_Float16)p1.x; r[2][1] = (_Float16)p1.y;
        r[3][0] = (_Float16)p1.z; r[3][1] = (_Float16)p1.w;
        r[4][0] = (_Float16)p2.x; r[4][1] = (_Float16)p2.y;
        r[5][0] = (_Float16)p2.z; r[5][1] = (_Float16)p2.w;
        r[6][0] = (_Float16)p3.x; r[6][1] = (_Float16)p3.y;
        r[7][0] = (_Float16)p3.z; r[7][1] = (_Float16)p3.w;
        *(uint4*)&As2[mf][sf * 8] = *(uint4*)&r[0];
        *(uint4*)&As2[mf][sf * 8 + 4] = *(uint4*)&r[4];
      }
#pragma unroll 1
      for (int nt = 0; nt < 8; ++nt) {
        __syncthreads();
        {
          const int kp = n >> 3, cg = n & 7;
          const float4* w0 = (const float4*)(WT0 + (size_t)(2 * kp) * NG + nt * 64 + cg * 8);
          const float4* w1 = (const float4*)(WT0 + (size_t)(2 * kp + 1) * NG + nt * 64 + cg * 8);
          float4 x0 = w0[0], x1 = w0[1];
          float4 y0 = w1[0], y1 = w1[1];
          h2_t r[8];
          r[0][0] = (_Float16)x0.x; r[0][1] = (_Float16)y0.x;
          r[1][0] = (_Float16)x0.y; r[1][1] = (_Float16)y0.y;
          r[2][0] = (_Float16)x0.z; r[2][1] = (_Float16)y0.z;
          r[3][0] = (_Float16)x0.w; r[3][1] = (_Float16)y0.w;
          r[4][0] = (_Float16)x1.x; r[4][1] = (_Float16)y1.x;
          r[5][0] = (_Float16)x1.y; r[5][1] = (_Float16)y1.y;
          r[6][0] = (_Float16)x1.z; r[6][1] = (_Float16)y1.z;
          r[7][0] = (_Float16)x1.w; r[7][1] = (_Float16)y1.w;
          *(uint4*)&Bs2[kp][cg * 8] = *(uint4*)&r[0];
          *(uint4*)&Bs2[kp][cg * 8 + 4] = *(uint4*)&r[4];
        }
        __syncthreads();

        float acc[2][4];
#pragma unroll
        for (int r = 0; r < 2; ++r)
#pragma unroll
          for (int q = 0; q < 4; ++q) acc[r][q] = 0.0f;
#pragma unroll 4
        for (int k4 = 0; k4 < 16; ++k4) {
          LDB ua0, ua1;
          ua0.u4 = *(const uint4*)&As2[ty * 2][k4 * 4];
          ua1.u4 = *(const uint4*)&As2[ty * 2 + 1][k4 * 4];
#pragma unroll
          for (int t = 0; t < 4; ++t) {
            LDB ub;
            ub.u4 = *(const uint4*)&Bs2[k4 * 4 + t][tx * 4];
            acc[0][0] = fdot2f(ua0.h[t], ub.h[0], acc[0][0]);
            acc[0][1] = fdot2f(ua0.h[t], ub.h[1], acc[0][1]);
            acc[0][2] = fdot2f(ua0.h[t], ub.h[2], acc[0][2]);
            acc[0][3] = fdot2f(ua0.h[t], ub.h[3], acc[0][3]);
            acc[1][0] = fdot2f(ua1.h[t], ub.h[0], acc[1][0]);
            acc[1][1] = fdot2f(ua1.h[t], ub.h[1], acc[1][1]);
            acc[1][2] = fdot2f(ua1.h[t], ub.h[2], acc[1][2]);
            acc[1][3] = fdot2f(ua1.h[t], ub.h[3], acc[1][3]);
          }
        }
        const int col = nt * 64 + tx * 4;
        float4 bv = *(const float4*)(b0 + col);
#pragma unroll
        for (int r = 0; r < 2; ++r) {
          __half2* d = (__half2*)(Xg + ((size_t)b * TT + t0x + ty * 2 + r) * NG + col);
          d[0] = __halves2half2(__float2half(acc[r][0] + bv.x),
                                __float2half(acc[r][1] + bv.y));
          d[1] = __halves2half2(__float2half(acc[r][2] + bv.z),
                                __float2half(acc[r][3] + bv.w));
        }
      }
      __syncthreads();   // drain Xg0 stores + protect As2
      if (n == 0) {
        __builtin_amdgcn_fence(__ATOMIC_RELEASE, "agent");
        atomicAdd(flagX + b * NCH + cc + LEAD, 1u);
      }
    }

    // ======== part X1: Xg1 for chunk cc (waits on h0) ========
    if (n == 0) {
      while (aload(flag0 + b * NCH + cc) < 1u) __builtin_amdgcn_s_sleep(8);
    }
    __syncthreads();
    __builtin_amdgcn_fence(__ATOMIC_ACQUIRE, "agent");

    const int t0 = cc * CH + half * 64;
    {
      const uint4* src = (const uint4*)(hstream + ((size_t)b * TT + t0 + mf) * HH + sf * 16);
      uint4 v0 = src[0], v1 = src[1];
      *(uint4*)&As2[mf][sf * 8] = v0;
      *(uint4*)&As2[mf][sf * 8 + 4] = v1;
    }
#pragma unroll 1
    for (int nt = 0; nt < 8; ++nt) {
      __syncthreads();
      {
        const int kp = n >> 3, cg = n & 7;
        const float4* w0 = (const float4*)(WT1 + (size_t)(2 * kp) * NG + nt * 64 + cg * 8);
        const float4* w1 = (const float4*)(WT1 + (size_t)(2 * kp + 1) * NG + nt * 64 + cg * 8);
        float4 x0 = w0[0], x1 = w0[1];
        float4 y0 = w1[0], y1 = w1[1];
        h2_t r[8];
        r[0][0] = (_Float16)x0.x; r[0][1] = (_Float16)y0.x;
        r[1][0] = (_Float16)x0.y; r[1][1] = (_Float16)y0.y;
        r[2][0] = (_Float16)x0.z; r[2][1] = (_Float16)y0.z;
        r[3][0] = (_Float16)x0.w; r[3][1] = (_Float16)y0.w;
        r[4][0] = (_Float16)x1.x; r[4][1] = (_Float16)y1.x;
        r[5][0] = (_Float16)x1.y; r[5][1] = (_Float16)y1.y;
        r[6][0] = (_Float16)x1.z; r[6][1] = (_Float16)y1.z;
        r[7][0] = (_Float16)x1.w; r[7][1] = (_Float16)y1.w;
        *(uint4*)&Bs2[kp][cg * 8] = *(uint4*)&r[0];
        *(uint4*)&Bs2[kp][cg * 8 + 4] = *(uint4*)&r[4];
      }
      __syncthreads();

      float acc[2][4];
#pragma unroll
      for (int r = 0; r < 2; ++r)
#pragma unroll
        for (int q = 0; q < 4; ++q) acc[r][q] = 0.0f;
#pragma unroll 4
      for (int k4 = 0; k4 < 16; ++k4) {
        LDB ua0, ua1;
        ua0.u4 = *(const uint4*)&As2[ty * 2][k4 * 4];
        ua1.u4 = *(const uint4*)&As2[ty * 2 + 1][k4 * 4];
#pragma unroll
        for (int t = 0; t < 4; ++t) {
          LDB ub;
          ub.u4 = *(const uint4*)&Bs2[k4 * 4 + t][tx * 4];
          acc[0][0] = fdot2f(ua0.h[t], ub.h[0], acc[0][0]);
          acc[0][1] = fdot2f(ua0.h[t], ub.h[1], acc[0][1]);
          acc[0][2] = fdot2f(ua0.h[t], ub.h[2], acc[0][2]);
          acc[0][3] = fdot2f(ua0.h[t], ub.h[3], acc[0][3]);
          acc[1][0] = fdot2f(ua1.h[t], ub.h[0], acc[1][0]);
          acc[1][1] = fdot2f(ua1.h[t], ub.h[1], acc[1][1]);
          acc[1][2] = fdot2f(ua1.h[t], ub.h[2], acc[1][2]);
          acc[1][3] = fdot2f(ua1.h[t], ub.h[3], acc[1][3]);
        }
      }
      const int col = nt * 64 + tx * 4;
      float4 bv = *(const float4*)(b1 + col);
#pragma unroll
      for (int r = 0; r < 2; ++r) {
        __half2* d = (__half2*)(Xg + ((size_t)b * TT + t0 + ty * 2 + r) * NG + col);
        d[0] = __halves2half2(__float2half(acc[r][0] + bv.x),
                              __float2half(acc[r][1] + bv.y));
        d[1] = __halves2half2(__float2half(acc[r][2] + bv.z),
                              __float2half(acc[r][3] + bv.w));
      }
    }
    __syncthreads();
    if (n == 0) {
      __builtin_amdgcn_fence(__ATOMIC_RELEASE, "agent");
      atomicAdd(flagC + b * NCH + cc, 1u);
    }
  }
}

// ---- role B: layer-1 recurrence (f32 FMA inner product) ----
__device__ __forceinline__ void roleB(int b, int n, char* smem,
    const __half* Xg, const float* __restrict__ Wh1,
    float* __restrict__ out, unsigned* flagC)
{
  const int j = n >> 2;
  const int p = n & 3;
  const bool tsel = (p == 2);

  float wh[4][32];
#pragma unroll
  for (int g = 0; g < 4; ++g) {
    const float4* ph = (const float4*)(Wh1 + (size_t)(g * 128 + j) * HH + p * 32);
#pragma unroll
    for (int k = 0; k < 8; ++k) {
      float4 v = ph[k];
      wh[g][4 * k + 0] = v.x;
      wh[g][4 * k + 1] = v.y;
      wh[g][4 * k + 2] = v.z;
      wh[g][4 * k + 3] = v.w;
    }
  }

  float(*hb)[HH] = (float(*)[HH])smem;
  if (n < HH) {
    hb[0][n] = 0.0f;
    hb[1][n] = 0.0f;
  }
  float c = 0.0f, hv = 0.0f;
  __syncthreads();

  const __half* xs = Xg + (size_t)b * TT * NG + p * 128 + j;
  float* outp = out + (size_t)b * TT * HH;
  float* hT = out + (size_t)BB * TT * HH;
  float* cT = hT + 2 * BB * HH;

#pragma unroll 1
  for (int cc = 0; cc < NCH; ++cc) {
    if (n == 0) {
      while (aload(flagC + b * NCH + cc) < 2u) __builtin_amdgcn_s_sleep(8);
    }
    __syncthreads();
    __builtin_amdgcn_fence(__ATOMIC_ACQUIRE, "agent");

    __half xg_c = xs[(size_t)(cc * CH) * NG];
#pragma unroll 1
    for (int s = 0; s < CH; ++s) {
      const int i = cc * CH + s;
      __half xg_n = (s + 1 < CH) ? xs[(size_t)(i + 1) * NG] : __float2half(0.0f);

      const float* H = hb[i & 1] + p * 32;
      float a0 = 0.f, a1 = 0.f, a2 = 0.f, a3 = 0.f;
#pragma unroll
      for (int q = 0; q < 8; ++q) {
        float4 u = *(const float4*)(H + q * 4);
        const int m = q * 4;
        a0 = fmaf(wh[0][m + 0], u.x, a0);
        a1 = fmaf(wh[1][m + 0], u.x, a1);
        a2 = fmaf(wh[2][m + 0], u.x, a2);
        a3 = fmaf(wh[3][m + 0], u.x, a3);
        a0 = fmaf(wh[0][m + 1], u.y, a0);
        a1 = fmaf(wh[1][m + 1], u.y, a1);
        a2 = fmaf(wh[2][m + 1], u.y, a2);
        a3 = fmaf(wh[3][m + 1], u.y, a3);
        a0 = fmaf(wh[0][m + 2], u.z, a0);
        a1 = fmaf(wh[1][m + 2], u.z, a1);
        a2 = fmaf(wh[2][m + 2], u.z, a2);
        a3 = fmaf(wh[3][m + 2], u.z, a3);
        a0 = fmaf(wh[0][m + 3], u.w, a0);
        a1 = fmaf(wh[1][m + 3], u.w, a1);
        a2 = fmaf(wh[2][m + 3], u.w, a2);
        a3 = fmaf(wh[3][m + 3], u.w, a3);
      }

      float k01 = (p & 1) ? a1 : a0;
      float u01 = (p & 1) ? a0 : a1;
      float r01 = k01 + dpp_xor1(u01);
      float k23 = (p & 1) ? a3 : a2;
      float u23 = (p & 1) ? a2 : a3;
      float r23 = k23 + dpp_xor1(u23);
      float kA = (p & 2) ? r23 : r01;
      float uA = (p & 2) ? r01 : r23;
      float sL = kA + dpp_xor2(uA);
      float aL = act_gate(sL + __half2float(xg_c), tsel);
      float fg = dpp_xor1(aL);
      float gg = dpp_xor2(aL);
      float og = dpp_xor2(fg);
      if (p == 0) {
        c = fg * c + aL * gg;
        hv = og * fast_tanh(c);
        hb[(i & 1) ^ 1][j] = hv;
        outp[(size_t)i * HH + j] = hv;
      }
      bar_lds();
      xg_c = xg_n;
    }
  }

  if (p == 0) {
    hT[BB * HH + b * HH + j] = hv;
    cT[BB * HH + b * HH + j] = c;
  }
}

__global__
__attribute__((amdgpu_flat_work_group_size(512, 512)))
void lstm_mega(__half* Xg, __half* hstream, const float* __restrict__ x,
               const float* __restrict__ Wh0,
               const float* __restrict__ Wh1,
               const float* __restrict__ WT0,
               const float* __restrict__ b0,
               const float* __restrict__ WT1,
               const float* __restrict__ b1,
               float* __restrict__ out,
               unsigned* flag0, unsigned* flagC, unsigned* flagX)
{
  extern __shared__ __align__(16) char smem[];   // DYN_LDS bytes: 1 WG/CU
  const int bid = blockIdx.x;
  const int n = threadIdx.x;
  if (bid < BB) {
    roleA(bid, n, smem, Xg, Wh0, out, hstream, flag0, flagX);
  } else if (bid < BB + 2 * BB) {
    roleC(bid - BB, n, smem, Xg, hstream, x, WT0, b0, WT1, b1,
          flag0, flagC, flagX);
  } else {
    roleB(bid - 3 * BB, n, smem, Xg, Wh1, out, flagC);
  }
}

// ---------------------------------------------------------------------------
extern "C" void kernel_launch(void* const* d_in, const int* in_sizes, int n_in,
                              void* d_out, int out_size, void* d_ws, size_t ws_size,
                              hipStream_t stream) {
  const float* x   = (const float*)d_in[0];
  const float* Wx0 = (const float*)d_in[1];
  const float* Wh0 = (const float*)d_in[2];
  const float* b0  = (const float*)d_in[3];
  const float* Wx1 = (const float*)d_in[4];
  const float* Wh1 = (const float*)d_in[5];
  const float* b1  = (const float*)d_in[6];
  float* out = (float*)d_out;

  // ws: Xg f16 [B*T][512] | hstream f16 [B*T][128] | WT0 | WT1 | flags x3
  char* base = (char*)d_ws;
  __half* Xg = (__half*)base;
  size_t off = (size_t)BB * TT * NG * sizeof(__half);      // 128 MB
  __half* hstream = (__half*)(base + off);
  off += (size_t)BB * TT * HH * sizeof(__half);            // +32 MB
  float* WT0 = (float*)(base + off);
  off += (size_t)II * NG * sizeof(float);
  float* WT1 = (float*)(base + off);
  off += (size_t)II * NG * sizeof(float);
  unsigned* flag0 = (unsigned*)(base + off);
  unsigned* flagC = flag0 + BB * NCH;
  unsigned* flagX = flagC + BB * NCH;

  hipFuncSetAttribute((const void*)lstm_mega,
                      hipFuncAttributeMaxDynamicSharedMemorySize, DYN_LDS);

  hipMemsetAsync(flag0, 0, 3 * (size_t)BB * NCH * sizeof(unsigned), stream);
  w_transpose2<<<512, 256, 0, stream>>>(Wx0, WT0, Wx1, WT1);
  // Prologue: Xg0 for chunks 0..LEAD-1 (rows [b*TT, b*TT+LEAD*CH))
  xg_gemm_pro<<<dim3(BB * 8, NG / 64), 256, 0, stream>>>(x, WT0, b0, Xg);
  lstm_mega<<<4 * BB, 512, DYN_LDS, stream>>>(Xg, hstream, x, Wh0, Wh1, WT0,
                                              b0, WT1, b1, out, flag0, flagC,
                                              flagX);
}

// Round 19
// 1833.017 us; speedup vs baseline: 1.0992x; 1.0117x over previous
//
#include <hip/hip_runtime.h>
#include <hip/hip_fp16.h>

// Problem constants
#define BB 64
#define TT 2048
#define II 128
#define HH 128
#define NG 512   // 4*H
#define CH 128   // pipeline chunk (steps)
#define NCH (TT / CH)
#define LEAD 4   // A's chunk lead (prologue covers chunks 0..LEAD-1)
#define DYN_LDS 81984  // > 160KiB/2 -> hardware places only ONE WG per CU
#define HPAD 140 // f32 h buffer: 128 + 4-float pad per 32-group (bank-spread)

typedef _Float16 h2_t __attribute__((ext_vector_type(2)));

#if defined(__has_builtin)
#if __has_builtin(__builtin_amdgcn_fdot2)
#define HAVE_FDOT2 1
#endif
#endif

__device__ __forceinline__ float fdot2f(h2_t a, h2_t b, float c) {
#ifdef HAVE_FDOT2
  return __builtin_amdgcn_fdot2(a, b, c, false);
#else
  return c + (float)a[0] * (float)b[0] + (float)a[1] * (float)b[1];
#endif
}

__device__ __forceinline__ float fast_sigmoid(float x) {
  float t = __builtin_amdgcn_exp2f(-1.4426950408889634f * x);
  return __builtin_amdgcn_rcpf(1.0f + t);
}
__device__ __forceinline__ float act_gate(float x, bool tanh_sel) {
  float xx = tanh_sel ? 2.0f * x : x;
  float s = fast_sigmoid(xx);
  return tanh_sel ? 2.0f * s - 1.0f : s;
}
__device__ __forceinline__ float fast_tanh(float x) {
  return 2.0f * fast_sigmoid(2.0f * x) - 1.0f;
}

__device__ __forceinline__ float dpp_xor1(float x) {
  return __int_as_float(__builtin_amdgcn_update_dpp(0, __float_as_int(x), 0xB1, 0xF, 0xF, true));
}
__device__ __forceinline__ float dpp_xor2(float x) {
  return __int_as_float(__builtin_amdgcn_update_dpp(0, __float_as_int(x), 0x4E, 0xF, 0xF, true));
}

// LDS-only barrier: lgkmcnt drain + s_barrier (no vmcnt drain).
__device__ __forceinline__ void bar_lds() {
  __builtin_amdgcn_fence(__ATOMIC_RELEASE, "workgroup", "local");
  __builtin_amdgcn_s_barrier();
  __builtin_amdgcn_fence(__ATOMIC_ACQUIRE, "workgroup", "local");
}

union LDB {
  uint4 u4;
  h2_t h[4];
};

__device__ __forceinline__ unsigned aload(unsigned* p) { return atomicAdd(p, 0u); }

// ---------------------------------------------------------------------------
// Transpose both Wx0 and Wx1: [512][128] -> [128][512]
// ---------------------------------------------------------------------------
__global__ void w_transpose2(const float* __restrict__ W0, float* __restrict__ T0,
                             const float* __restrict__ W1, float* __restrict__ T1) {
  int bid = blockIdx.x;
  const float* W = (bid < 256) ? W0 : W1;
  float* T = (bid < 256) ? T0 : T1;
  int idx = (bid & 255) * 256 + threadIdx.x;
  int n = idx >> 7;
  int k = idx & 127;
  T[k * NG + n] = W[idx];
}

// ---------------------------------------------------------------------------
// Prologue GEMM: Xg0 for chunks 0..LEAD-1 (rows [b*TT, b*TT+LEAD*CH)).
// ---------------------------------------------------------------------------
__global__ __launch_bounds__(256) void xg_gemm_pro(const float* __restrict__ X,
                                                   const float* __restrict__ WT,
                                                   const float* __restrict__ bias,
                                                   __half* __restrict__ Xg) {
  __shared__ float As[64][132];
  __shared__ float Bs[128][64];
  const int bx = blockIdx.x;
  const size_t m0 = (size_t)(bx >> 3) * TT + (bx & 7) * 64;
  const int n0 = blockIdx.y * 64;
  const int tid = threadIdx.x;

  {
    const float4* xv = (const float4*)(X + m0 * II);
#pragma unroll
    for (int r = 0; r < 8; ++r) {
      int f = tid + 256 * r;
      int m = f >> 5;
      int c4 = f & 31;
      float4 v = xv[m * 32 + c4];
      *(float4*)&As[m][c4 * 4] = v;
    }
  }
  {
#pragma unroll
    for (int r = 0; r < 8; ++r) {
      int f = tid + 256 * r;
      int k = f >> 4;
      int q = f & 15;
      float4 v = *(const float4*)(WT + (size_t)k * NG + n0 + q * 4);
      *(float4*)&Bs[k][q * 4] = v;
    }
  }
  __syncthreads();

  const int tx = tid & 15;
  const int ty = tid >> 4;
  float acc[4][4];
#pragma unroll
  for (int i = 0; i < 4; ++i)
#pragma unroll
    for (int j = 0; j < 4; ++j) acc[i][j] = 0.0f;

#pragma unroll 4
  for (int k = 0; k < 128; ++k) {
    float a0 = As[ty * 4 + 0][k];
    float a1 = As[ty * 4 + 1][k];
    float a2 = As[ty * 4 + 2][k];
    float a3 = As[ty * 4 + 3][k];
    float4 bv = *(const float4*)&Bs[k][tx * 4];
    acc[0][0] = fmaf(a0, bv.x, acc[0][0]);
    acc[0][1] = fmaf(a0, bv.y, acc[0][1]);
    acc[0][2] = fmaf(a0, bv.z, acc[0][2]);
    acc[0][3] = fmaf(a0, bv.w, acc[0][3]);
    acc[1][0] = fmaf(a1, bv.x, acc[1][0]);
    acc[1][1] = fmaf(a1, bv.y, acc[1][1]);
    acc[1][2] = fmaf(a1, bv.z, acc[1][2]);
    acc[1][3] = fmaf(a1, bv.w, acc[1][3]);
    acc[2][0] = fmaf(a2, bv.x, acc[2][0]);
    acc[2][1] = fmaf(a2, bv.y, acc[2][1]);
    acc[2][2] = fmaf(a2, bv.z, acc[2][2]);
    acc[2][3] = fmaf(a2, bv.w, acc[2][3]);
    acc[3][0] = fmaf(a3, bv.x, acc[3][0]);
    acc[3][1] = fmaf(a3, bv.y, acc[3][1]);
    acc[3][2] = fmaf(a3, bv.z, acc[3][2]);
    acc[3][3] = fmaf(a3, bv.w, acc[3][3]);
  }

  float4 bvec = *(const float4*)(bias + n0 + tx * 4);
#pragma unroll
  for (int i = 0; i < 4; ++i) {
    size_t m = m0 + ty * 4 + i;
    __half2* dst = (__half2*)(Xg + m * NG + n0 + tx * 4);
    dst[0] = __halves2half2(__float2half(acc[i][0] + bvec.x),
                            __float2half(acc[i][1] + bvec.y));
    dst[1] = __halves2half2(__float2half(acc[i][2] + bvec.z),
                            __float2half(acc[i][3] + bvec.w));
  }
}

// ===========================================================================
// Mega kernel: 256 WGs, ONE per CU (dynamic LDS > 160KiB/2).
//   [0,64):    role A — L0 recurrence (waits flagX for cc>=LEAD), flag0/chunk
//   [64,192):  role C — per iter cc: Xg0(cc+LEAD) -> flagX, then wait
//              flag0(cc) -> Xg1(cc)=h0@Wx1^T+b1 (in place) -> flagC
//   [192,256): role B — L1 recurrence on Xg1 chunks (waits flagC>=2)
// Recurrence: f32 FMA inner product (2 cyc/inst). h stored f32 in LDS with
// a 4-float pad per 32-group (HPAD=140): slice bases {0,36,72,108} floats
// hit bank quads {0-3,4-7,8-11,12-15} -> conflict-free broadcast reads
// (fixes R18's 71M 4-way conflicts from the unpadded 128B-stride layout).
// ===========================================================================

// ---- role A: layer-0 recurrence (f32 FMA, padded h) ----
__device__ __forceinline__ void roleA(int b, int n, char* smem,
    const __half* Xg, const float* __restrict__ Wh0,
    float* __restrict__ out, __half* hstream,
    unsigned* flag0, unsigned* flagX)
{
  const int j = n >> 2;
  const int p = n & 3;
  const bool tsel = (p == 2);
  const int jw = j + ((j >> 5) << 2);   // padded write offset

  float wh[4][32];
#pragma unroll
  for (int g = 0; g < 4; ++g) {
    const float4* ph = (const float4*)(Wh0 + (size_t)(g * 128 + j) * HH + p * 32);
#pragma unroll
    for (int k = 0; k < 8; ++k) {
      float4 v = ph[k];
      wh[g][4 * k + 0] = v.x;
      wh[g][4 * k + 1] = v.y;
      wh[g][4 * k + 2] = v.z;
      wh[g][4 * k + 3] = v.w;
    }
  }

  float(*hb)[HPAD] = (float(*)[HPAD])smem;   // padded f32 h, double-buffered
  if (n < HH) {
    hb[0][n + ((n >> 5) << 2)] = 0.0f;
    hb[1][n + ((n >> 5) << 2)] = 0.0f;
  }
  float c = 0.0f, hv = 0.0f;
  __syncthreads();

  const __half* xs = Xg + (size_t)b * TT * NG + p * 128 + j;
  float* hT = out + (size_t)BB * TT * HH;
  float* cT = hT + 2 * BB * HH;
  __half* hsp = hstream + (size_t)b * TT * HH + j;

#pragma unroll 1
  for (int cc = 0; cc < NCH; ++cc) {
    if (cc >= LEAD) {
      if (n == 0) {
        while (aload(flagX + b * NCH + cc) < 2u) __builtin_amdgcn_s_sleep(1);
      }
      __syncthreads();
      __builtin_amdgcn_fence(__ATOMIC_ACQUIRE, "agent");
    }
    __half xg_c = xs[(size_t)(cc * CH) * NG];

#pragma unroll 1
    for (int s = 0; s < CH; ++s) {
      const int i = cc * CH + s;
      __half xg_n = (s + 1 < CH) ? xs[(size_t)(i + 1) * NG] : __float2half(0.0f);

      const float* H = hb[i & 1] + p * 36;   // padded slice base
      float a0 = 0.f, a1 = 0.f, a2 = 0.f, a3 = 0.f;
#pragma unroll
      for (int q = 0; q < 8; ++q) {
        float4 u = *(const float4*)(H + q * 4);
        const int m = q * 4;
        a0 = fmaf(wh[0][m + 0], u.x, a0);
        a1 = fmaf(wh[1][m + 0], u.x, a1);
        a2 = fmaf(wh[2][m + 0], u.x, a2);
        a3 = fmaf(wh[3][m + 0], u.x, a3);
        a0 = fmaf(wh[0][m + 1], u.y, a0);
        a1 = fmaf(wh[1][m + 1], u.y, a1);
        a2 = fmaf(wh[2][m + 1], u.y, a2);
        a3 = fmaf(wh[3][m + 1], u.y, a3);
        a0 = fmaf(wh[0][m + 2], u.z, a0);
        a1 = fmaf(wh[1][m + 2], u.z, a1);
        a2 = fmaf(wh[2][m + 2], u.z, a2);
        a3 = fmaf(wh[3][m + 2], u.z, a3);
        a0 = fmaf(wh[0][m + 3], u.w, a0);
        a1 = fmaf(wh[1][m + 3], u.w, a1);
        a2 = fmaf(wh[2][m + 3], u.w, a2);
        a3 = fmaf(wh[3][m + 3], u.w, a3);
      }

      float k01 = (p & 1) ? a1 : a0;
      float u01 = (p & 1) ? a0 : a1;
      float r01 = k01 + dpp_xor1(u01);
      float k23 = (p & 1) ? a3 : a2;
      float u23 = (p & 1) ? a2 : a3;
      float r23 = k23 + dpp_xor1(u23);
      float kA = (p & 2) ? r23 : r01;
      float uA = (p & 2) ? r01 : r23;
      float sL = kA + dpp_xor2(uA);
      float aL = act_gate(sL + __half2float(xg_c), tsel);
      float fg = dpp_xor1(aL);
      float gg = dpp_xor2(aL);
      float og = dpp_xor2(fg);
      if (p == 0) {
        c = fg * c + aL * gg;
        hv = og * fast_tanh(c);
        hb[(i & 1) ^ 1][jw] = hv;
        *(_Float16*)(hsp + (size_t)i * HH) = (_Float16)hv;
      }
      bar_lds();
      xg_c = xg_n;
    }
    __syncthreads();   // drains hstream stores (vmcnt)
    if (n == 0) {
      __builtin_amdgcn_fence(__ATOMIC_RELEASE, "agent");
      atomicExch(flag0 + b * NCH + cc, 1u);
    }
  }

  if (p == 0) {
    hT[b * HH + j] = hv;
    cT[b * HH + j] = c;
  }
}

// ---- role C: Xg0(cc+LEAD) production then Xg1(cc) bridge GEMM ----
__device__ __forceinline__ void roleC(int cidx, int n, char* smem,
    __half* Xg, const __half* hstream, const float* __restrict__ x,
    const float* __restrict__ WT0, const float* __restrict__ b0,
    const float* __restrict__ WT1, const float* __restrict__ b1,
    unsigned* flag0, unsigned* flagC, unsigned* flagX)
{
  const int b = cidx >> 1;
  const int half = cidx & 1;
  h2_t(*As2)[68] = (h2_t(*)[68])smem;                    // [64][68] h2
  h2_t(*Bs2)[64] = (h2_t(*)[64])(smem + 64 * 68 * 4);    // [64][64] h2

  const int ty = n >> 4;
  const int tx = n & 15;
  const int mf = n >> 3;   // fill row
  const int sf = n & 7;    // fill segment

#pragma unroll 1
  for (int cc = 0; cc < NCH; ++cc) {
    // ======== part X0: Xg0 for chunk cc+LEAD (input-only, no waits) ========
    if (cc + LEAD < NCH) {
      const int t0x = (cc + LEAD) * CH + half * 64;
      {
        const float4* sx = (const float4*)(x + ((size_t)b * TT + t0x + mf) * II + sf * 16);
        float4 p0 = sx[0], p1 = sx[1], p2 = sx[2], p3 = sx[3];
        h2_t r[8];
        r[0][0] = (_Float16)p0.x; r[0][1] = (_Float16)p0.y;
        r[1][0] = (_Float16)p0.z; r[1][1] = (_Float16)p0.w;
        r[2][0] = (_Float16)p1.x; r[2][1] = (_Float16)p1.y;
        r[3][0] = (_Float16)p1.z; r[3][1] = (_Float16)p1.w;
        r[4][0] = (_Float16)p2.x; r[4][1] = (_Float16)p2.y;
        r[5][0] = (_Float16)p2.z; r[5][1] = (_Float16)p2.w;
        r[6][0] = (_Float16)p3.x; r[6][1] = (_Float16)p3.y;
        r[7][0] = (_Float16)p3.z; r[7][1] = (_Float16)p3.w;
        *(uint4*)&As2[mf][sf * 8] = *(uint4*)&r[0];
        *(uint4*)&As2[mf][sf * 8 + 4] = *(uint4*)&r[4];
      }
#pragma unroll 1
      for (int nt = 0; nt < 8; ++nt) {
        __syncthreads();
        {
          const int kp = n >> 3, cg = n & 7;
          const float4* w0 = (const float4*)(WT0 + (size_t)(2 * kp) * NG + nt * 64 + cg * 8);
          const float4* w1 = (const float4*)(WT0 + (size_t)(2 * kp + 1) * NG + nt * 64 + cg * 8);
          float4 x0 = w0[0], x1 = w0[1];
          float4 y0 = w1[0], y1 = w1[1];
          h2_t r[8];
          r[0][0] = (_Float16)x0.x; r[0][1] = (_Float16)y0.x;
          r[1][0] = (_Float16)x0.y; r[1][1] = (_Float16)y0.y;
          r[2][0] = (_Float16)x0.z; r[2][1] = (_Float16)y0.z;
          r[3][0] = (_Float16)x0.w; r[3][1] = (_Float16)y0.w;
          r[4][0] = (_Float16)x1.x; r[4][1] = (_Float16)y1.x;
          r[5][0] = (_Float16)x1.y; r[5][1] = (_Float16)y1.y;
          r[6][0] = (_Float16)x1.z; r[6][1] = (_Float16)y1.z;
          r[7][0] = (_Float16)x1.w; r[7][1] = (_Float16)y1.w;
          *(uint4*)&Bs2[kp][cg * 8] = *(uint4*)&r[0];
          *(uint4*)&Bs2[kp][cg * 8 + 4] = *(uint4*)&r[4];
        }
        __syncthreads();

        float acc[2][4];
#pragma unroll
        for (int r = 0; r < 2; ++r)
#pragma unroll
          for (int q = 0; q < 4; ++q) acc[r][q] = 0.0f;
#pragma unroll 4
        for (int k4 = 0; k4 < 16; ++k4) {
          LDB ua0, ua1;
          ua0.u4 = *(const uint4*)&As2[ty * 2][k4 * 4];
          ua1.u4 = *(const uint4*)&As2[ty * 2 + 1][k4 * 4];
#pragma unroll
          for (int t = 0; t < 4; ++t) {
            LDB ub;
            ub.u4 = *(const uint4*)&Bs2[k4 * 4 + t][tx * 4];
            acc[0][0] = fdot2f(ua0.h[t], ub.h[0], acc[0][0]);
            acc[0][1] = fdot2f(ua0.h[t], ub.h[1], acc[0][1]);
            acc[0][2] = fdot2f(ua0.h[t], ub.h[2], acc[0][2]);
            acc[0][3] = fdot2f(ua0.h[t], ub.h[3], acc[0][3]);
            acc[1][0] = fdot2f(ua1.h[t], ub.h[0], acc[1][0]);
            acc[1][1] = fdot2f(ua1.h[t], ub.h[1], acc[1][1]);
            acc[1][2] = fdot2f(ua1.h[t], ub.h[2], acc[1][2]);
            acc[1][3] = fdot2f(ua1.h[t], ub.h[3], acc[1][3]);
          }
        }
        const int col = nt * 64 + tx * 4;
        float4 bv = *(const float4*)(b0 + col);
#pragma unroll
        for (int r = 0; r < 2; ++r) {
          __half2* d = (__half2*)(Xg + ((size_t)b * TT + t0x + ty * 2 + r) * NG + col);
          d[0] = __halves2half2(__float2half(acc[r][0] + bv.x),
                                __float2half(acc[r][1] + bv.y));
          d[1] = __halves2half2(__float2half(acc[r][2] + bv.z),
                                __float2half(acc[r][3] + bv.w));
        }
      }
      __syncthreads();   // drain Xg0 stores + protect As2
      if (n == 0) {
        __builtin_amdgcn_fence(__ATOMIC_RELEASE, "agent");
        atomicAdd(flagX + b * NCH + cc + LEAD, 1u);
      }
    }

    // ======== part X1: Xg1 for chunk cc (waits on h0) ========
    if (n == 0) {
      while (aload(flag0 + b * NCH + cc) < 1u) __builtin_amdgcn_s_sleep(8);
    }
    __syncthreads();
    __builtin_amdgcn_fence(__ATOMIC_ACQUIRE, "agent");

    const int t0 = cc * CH + half * 64;
    {
      const uint4* src = (const uint4*)(hstream + ((size_t)b * TT + t0 + mf) * HH + sf * 16);
      uint4 v0 = src[0], v1 = src[1];
      *(uint4*)&As2[mf][sf * 8] = v0;
      *(uint4*)&As2[mf][sf * 8 + 4] = v1;
    }
#pragma unroll 1
    for (int nt = 0; nt < 8; ++nt) {
      __syncthreads();
      {
        const int kp = n >> 3, cg = n & 7;
        const float4* w0 = (const float4*)(WT1 + (size_t)(2 * kp) * NG + nt * 64 + cg * 8);
        const float4* w1 = (const float4*)(WT1 + (size_t)(2 * kp + 1) * NG + nt * 64 + cg * 8);
        float4 x0 = w0[0], x1 = w0[1];
        float4 y0 = w1[0], y1 = w1[1];
        h2_t r[8];
        r[0][0] = (_Float16)x0.x; r[0][1] = (_Float16)y0.x;
        r[1][0] = (_Float16)x0.y; r[1][1] = (_Float16)y0.y;
        r[2][0] = (_Float16)x0.z; r[2][1] = (_Float16)y0.z;
        r[3][0] = (_Float16)x0.w; r[3][1] = (_Float16)y0.w;
        r[4][0] = (_Float16)x1.x; r[4][1] = (_Float16)y1.x;
        r[5][0] = (_Float16)x1.y; r[5][1] = (_Float16)y1.y;
        r[6][0] = (_Float16)x1.z; r[6][1] = (_Float16)y1.z;
        r[7][0] = (_Float16)x1.w; r[7][1] = (_Float16)y1.w;
        *(uint4*)&Bs2[kp][cg * 8] = *(uint4*)&r[0];
        *(uint4*)&Bs2[kp][cg * 8 + 4] = *(uint4*)&r[4];
      }
      __syncthreads();

      float acc[2][4];
#pragma unroll
      for (int r = 0; r < 2; ++r)
#pragma unroll
        for (int q = 0; q < 4; ++q) acc[r][q] = 0.0f;
#pragma unroll 4
      for (int k4 = 0; k4 < 16; ++k4) {
        LDB ua0, ua1;
        ua0.u4 = *(const uint4*)&As2[ty * 2][k4 * 4];
        ua1.u4 = *(const uint4*)&As2[ty * 2 + 1][k4 * 4];
#pragma unroll
        for (int t = 0; t < 4; ++t) {
          LDB ub;
          ub.u4 = *(const uint4*)&Bs2[k4 * 4 + t][tx * 4];
          acc[0][0] = fdot2f(ua0.h[t], ub.h[0], acc[0][0]);
          acc[0][1] = fdot2f(ua0.h[t], ub.h[1], acc[0][1]);
          acc[0][2] = fdot2f(ua0.h[t], ub.h[2], acc[0][2]);
          acc[0][3] = fdot2f(ua0.h[t], ub.h[3], acc[0][3]);
          acc[1][0] = fdot2f(ua1.h[t], ub.h[0], acc[1][0]);
          acc[1][1] = fdot2f(ua1.h[t], ub.h[1], acc[1][1]);
          acc[1][2] = fdot2f(ua1.h[t], ub.h[2], acc[1][2]);
          acc[1][3] = fdot2f(ua1.h[t], ub.h[3], acc[1][3]);
        }
      }
      const int col = nt * 64 + tx * 4;
      float4 bv = *(const float4*)(b1 + col);
#pragma unroll
      for (int r = 0; r < 2; ++r) {
        __half2* d = (__half2*)(Xg + ((size_t)b * TT + t0 + ty * 2 + r) * NG + col);
        d[0] = __halves2half2(__float2half(acc[r][0] + bv.x),
                              __float2half(acc[r][1] + bv.y));
        d[1] = __halves2half2(__float2half(acc[r][2] + bv.z),
                              __float2half(acc[r][3] + bv.w));
      }
    }
    __syncthreads();
    if (n == 0) {
      __builtin_amdgcn_fence(__ATOMIC_RELEASE, "agent");
      atomicAdd(flagC + b * NCH + cc, 1u);
    }
  }
}

// ---- role B: layer-1 recurrence (f32 FMA, padded h) ----
__device__ __forceinline__ void roleB(int b, int n, char* smem,
    const __half* Xg, const float* __restrict__ Wh1,
    float* __restrict__ out, unsigned* flagC)
{
  const int j = n >> 2;
  const int p = n & 3;
  const bool tsel = (p == 2);
  const int jw = j + ((j >> 5) << 2);

  float wh[4][32];
#pragma unroll
  for (int g = 0; g < 4; ++g) {
    const float4* ph = (const float4*)(Wh1 + (size_t)(g * 128 + j) * HH + p * 32);
#pragma unroll
    for (int k = 0; k < 8; ++k) {
      float4 v = ph[k];
      wh[g][4 * k + 0] = v.x;
      wh[g][4 * k + 1] = v.y;
      wh[g][4 * k + 2] = v.z;
      wh[g][4 * k + 3] = v.w;
    }
  }

  float(*hb)[HPAD] = (float(*)[HPAD])smem;
  if (n < HH) {
    hb[0][n + ((n >> 5) << 2)] = 0.0f;
    hb[1][n + ((n >> 5) << 2)] = 0.0f;
  }
  float c = 0.0f, hv = 0.0f;
  __syncthreads();

  const __half* xs = Xg + (size_t)b * TT * NG + p * 128 + j;
  float* outp = out + (size_t)b * TT * HH;
  float* hT = out + (size_t)BB * TT * HH;
  float* cT = hT + 2 * BB * HH;

#pragma unroll 1
  for (int cc = 0; cc < NCH; ++cc) {
    if (n == 0) {
      while (aload(flagC + b * NCH + cc) < 2u) __builtin_amdgcn_s_sleep(8);
    }
    __syncthreads();
    __builtin_amdgcn_fence(__ATOMIC_ACQUIRE, "agent");

    __half xg_c = xs[(size_t)(cc * CH) * NG];
#pragma unroll 1
    for (int s = 0; s < CH; ++s) {
      const int i = cc * CH + s;
      __half xg_n = (s + 1 < CH) ? xs[(size_t)(i + 1) * NG] : __float2half(0.0f);

      const float* H = hb[i & 1] + p * 36;
      float a0 = 0.f, a1 = 0.f, a2 = 0.f, a3 = 0.f;
#pragma unroll
      for (int q = 0; q < 8; ++q) {
        float4 u = *(const float4*)(H + q * 4);
        const int m = q * 4;
        a0 = fmaf(wh[0][m + 0], u.x, a0);
        a1 = fmaf(wh[1][m + 0], u.x, a1);
        a2 = fmaf(wh[2][m + 0], u.x, a2);
        a3 = fmaf(wh[3][m + 0], u.x, a3);
        a0 = fmaf(wh[0][m + 1], u.y, a0);
        a1 = fmaf(wh[1][m + 1], u.y, a1);
        a2 = fmaf(wh[2][m + 1], u.y, a2);
        a3 = fmaf(wh[3][m + 1], u.y, a3);
        a0 = fmaf(wh[0][m + 2], u.z, a0);
        a1 = fmaf(wh[1][m + 2], u.z, a1);
        a2 = fmaf(wh[2][m + 2], u.z, a2);
        a3 = fmaf(wh[3][m + 2], u.z, a3);
        a0 = fmaf(wh[0][m + 3], u.w, a0);
        a1 = fmaf(wh[1][m + 3], u.w, a1);
        a2 = fmaf(wh[2][m + 3], u.w, a2);
        a3 = fmaf(wh[3][m + 3], u.w, a3);
      }

      float k01 = (p & 1) ? a1 : a0;
      float u01 = (p & 1) ? a0 : a1;
      float r01 = k01 + dpp_xor1(u01);
      float k23 = (p & 1) ? a3 : a2;
      float u23 = (p & 1) ? a2 : a3;
      float r23 = k23 + dpp_xor1(u23);
      float kA = (p & 2) ? r23 : r01;
      float uA = (p & 2) ? r01 : r23;
      float sL = kA + dpp_xor2(uA);
      float aL = act_gate(sL + __half2float(xg_c), tsel);
      float fg = dpp_xor1(aL);
      float gg = dpp_xor2(aL);
      float og = dpp_xor2(fg);
      if (p == 0) {
        c = fg * c + aL * gg;
        hv = og * fast_tanh(c);
        hb[(i & 1) ^ 1][jw] = hv;
        outp[(size_t)i * HH + j] = hv;
      }
      bar_lds();
      xg_c = xg_n;
    }
  }

  if (p == 0) {
    hT[BB * HH + b * HH + j] = hv;
    cT[BB * HH + b * HH + j] = c;
  }
}

__global__
__attribute__((amdgpu_flat_work_group_size(512, 512)))
void lstm_mega(__half* Xg, __half* hstream, const float* __restrict__ x,
               const float* __restrict__ Wh0,
               const float* __restrict__ Wh1,
               const float* __restrict__ WT0,
               const float* __restrict__ b0,
               const float* __restrict__ WT1,
               const float* __restrict__ b1,
               float* __restrict__ out,
               unsigned* flag0, unsigned* flagC, unsigned* flagX)
{
  extern __shared__ __align__(16) char smem[];   // DYN_LDS bytes: 1 WG/CU
  const int bid = blockIdx.x;
  const int n = threadIdx.x;
  if (bid < BB) {
    roleA(bid, n, smem, Xg, Wh0, out, hstream, flag0, flagX);
  } else if (bid < BB + 2 * BB) {
    roleC(bid - BB, n, smem, Xg, hstream, x, WT0, b0, WT1, b1,
          flag0, flagC, flagX);
  } else {
    roleB(bid - 3 * BB, n, smem, Xg, Wh1, out, flagC);
  }
}

// ---------------------------------------------------------------------------
extern "C" void kernel_launch(void* const* d_in, const int* in_sizes, int n_in,
                              void* d_out, int out_size, void* d_ws, size_t ws_size,
                              hipStream_t stream) {
  const float* x   = (const float*)d_in[0];
  const float* Wx0 = (const float*)d_in[1];
  const float* Wh0 = (const float*)d_in[2];
  const float* b0  = (const float*)d_in[3];
  const float* Wx1 = (const float*)d_in[4];
  const float* Wh1 = (const float*)d_in[5];
  const float* b1  = (const float*)d_in[6];
  float* out = (float*)d_out;

  // ws: Xg f16 [B*T][512] | hstream f16 [B*T][128] | WT0 | WT1 | flags x3
  char* base = (char*)d_ws;
  __half* Xg = (__half*)base;
  size_t off = (size_t)BB * TT * NG * sizeof(__half);      // 128 MB
  __half* hstream = (__half*)(base + off);
  off += (size_t)BB * TT * HH * sizeof(__half);            // +32 MB
  float* WT0 = (float*)(base + off);
  off += (size_t)II * NG * sizeof(float);
  float* WT1 = (float*)(base + off);
  off += (size_t)II * NG * sizeof(float);
  unsigned* flag0 = (unsigned*)(base + off);
  unsigned* flagC = flag0 + BB * NCH;
  unsigned* flagX = flagC + BB * NCH;

  hipFuncSetAttribute((const void*)lstm_mega,
                      hipFuncAttributeMaxDynamicSharedMemorySize, DYN_LDS);

  hipMemsetAsync(flag0, 0, 3 * (size_t)BB * NCH * sizeof(unsigned), stream);
  w_transpose2<<<512, 256, 0, stream>>>(Wx0, WT0, Wx1, WT1);
  // Prologue: Xg0 for chunks 0..LEAD-1 (rows [b*TT, b*TT+LEAD*CH))
  xg_gemm_pro<<<dim3(BB * 8, NG / 64), 256, 0, stream>>>(x, WT0, b0, Xg);
  lstm_mega<<<4 * BB, 512, DYN_LDS, stream>>>(Xg, hstream, x, Wh0, Wh1, WT0,
                                              b0, WT1, b1, out, flag0, flagC,
                                              flagX);
}

// Round 20
// 1413.580 us; speedup vs baseline: 1.4254x; 1.2967x over previous
//
#include <hip/hip_runtime.h>
#include <hip/hip_fp16.h>

// Problem constants
#define BB 64
#define TT 2048
#define II 128
#define HH 128
#define NG 512   // 4*H
#define CH 128   // pipeline chunk (steps)
#define NCH (TT / CH)
#define LEAD 4   // A's chunk lead (prologue covers chunks 0..LEAD-1)
#define DYN_LDS 81984  // > 160KiB/2 -> hardware places only ONE WG per CU

typedef _Float16 h2_t __attribute__((ext_vector_type(2)));

#if defined(__has_builtin)
#if __has_builtin(__builtin_amdgcn_fdot2)
#define HAVE_FDOT2 1
#endif
#endif

__device__ __forceinline__ float fdot2f(h2_t a, h2_t b, float c) {
#ifdef HAVE_FDOT2
  return __builtin_amdgcn_fdot2(a, b, c, false);
#else
  return c + (float)a[0] * (float)b[0] + (float)a[1] * (float)b[1];
#endif
}

__device__ __forceinline__ float fast_sigmoid(float x) {
  float t = __builtin_amdgcn_exp2f(-1.4426950408889634f * x);
  return __builtin_amdgcn_rcpf(1.0f + t);
}
__device__ __forceinline__ float act_gate(float x, bool tanh_sel) {
  float xx = tanh_sel ? 2.0f * x : x;
  float s = fast_sigmoid(xx);
  return tanh_sel ? 2.0f * s - 1.0f : s;
}
__device__ __forceinline__ float fast_tanh(float x) {
  return 2.0f * fast_sigmoid(2.0f * x) - 1.0f;
}

__device__ __forceinline__ float dpp_xor1(float x) {
  return __int_as_float(__builtin_amdgcn_update_dpp(0, __float_as_int(x), 0xB1, 0xF, 0xF, true));
}
__device__ __forceinline__ float dpp_xor2(float x) {
  return __int_as_float(__builtin_amdgcn_update_dpp(0, __float_as_int(x), 0x4E, 0xF, 0xF, true));
}

// LDS-only barrier: lgkmcnt drain + s_barrier (no vmcnt drain).
__device__ __forceinline__ void bar_lds() {
  __builtin_amdgcn_fence(__ATOMIC_RELEASE, "workgroup", "local");
  __builtin_amdgcn_s_barrier();
  __builtin_amdgcn_fence(__ATOMIC_ACQUIRE, "workgroup", "local");
}

union LD4 {
  float4 f4;
  h2_t h[4];
};
union LDB {
  uint4 u4;
  h2_t h[4];
};

__device__ __forceinline__ unsigned aload(unsigned* p) { return atomicAdd(p, 0u); }

// ---------------------------------------------------------------------------
// Transpose both Wx0 and Wx1: [512][128] -> [128][512]
// ---------------------------------------------------------------------------
__global__ void w_transpose2(const float* __restrict__ W0, float* __restrict__ T0,
                             const float* __restrict__ W1, float* __restrict__ T1) {
  int bid = blockIdx.x;
  const float* W = (bid < 256) ? W0 : W1;
  float* T = (bid < 256) ? T0 : T1;
  int idx = (bid & 255) * 256 + threadIdx.x;
  int n = idx >> 7;
  int k = idx & 127;
  T[k * NG + n] = W[idx];
}

// ---------------------------------------------------------------------------
// Prologue GEMM: Xg0 for chunks 0..LEAD-1 (rows [b*TT, b*TT+LEAD*CH)).
// grid.x = BB*8 (8 row-blocks of 64 = 512 rows/batch), grid.y = 8.
// ---------------------------------------------------------------------------
__global__ __launch_bounds__(256) void xg_gemm_pro(const float* __restrict__ X,
                                                   const float* __restrict__ WT,
                                                   const float* __restrict__ bias,
                                                   __half* __restrict__ Xg) {
  __shared__ float As[64][132];
  __shared__ float Bs[128][64];
  const int bx = blockIdx.x;
  const size_t m0 = (size_t)(bx >> 3) * TT + (bx & 7) * 64;
  const int n0 = blockIdx.y * 64;
  const int tid = threadIdx.x;

  {
    const float4* xv = (const float4*)(X + m0 * II);
#pragma unroll
    for (int r = 0; r < 8; ++r) {
      int f = tid + 256 * r;
      int m = f >> 5;
      int c4 = f & 31;
      float4 v = xv[m * 32 + c4];
      *(float4*)&As[m][c4 * 4] = v;
    }
  }
  {
#pragma unroll
    for (int r = 0; r < 8; ++r) {
      int f = tid + 256 * r;
      int k = f >> 4;
      int q = f & 15;
      float4 v = *(const float4*)(WT + (size_t)k * NG + n0 + q * 4);
      *(float4*)&Bs[k][q * 4] = v;
    }
  }
  __syncthreads();

  const int tx = tid & 15;
  const int ty = tid >> 4;
  float acc[4][4];
#pragma unroll
  for (int i = 0; i < 4; ++i)
#pragma unroll
    for (int j = 0; j < 4; ++j) acc[i][j] = 0.0f;

#pragma unroll 4
  for (int k = 0; k < 128; ++k) {
    float a0 = As[ty * 4 + 0][k];
    float a1 = As[ty * 4 + 1][k];
    float a2 = As[ty * 4 + 2][k];
    float a3 = As[ty * 4 + 3][k];
    float4 bv = *(const float4*)&Bs[k][tx * 4];
    acc[0][0] = fmaf(a0, bv.x, acc[0][0]);
    acc[0][1] = fmaf(a0, bv.y, acc[0][1]);
    acc[0][2] = fmaf(a0, bv.z, acc[0][2]);
    acc[0][3] = fmaf(a0, bv.w, acc[0][3]);
    acc[1][0] = fmaf(a1, bv.x, acc[1][0]);
    acc[1][1] = fmaf(a1, bv.y, acc[1][1]);
    acc[1][2] = fmaf(a1, bv.z, acc[1][2]);
    acc[1][3] = fmaf(a1, bv.w, acc[1][3]);
    acc[2][0] = fmaf(a2, bv.x, acc[2][0]);
    acc[2][1] = fmaf(a2, bv.y, acc[2][1]);
    acc[2][2] = fmaf(a2, bv.z, acc[2][2]);
    acc[2][3] = fmaf(a2, bv.w, acc[2][3]);
    acc[3][0] = fmaf(a3, bv.x, acc[3][0]);
    acc[3][1] = fmaf(a3, bv.y, acc[3][1]);
    acc[3][2] = fmaf(a3, bv.z, acc[3][2]);
    acc[3][3] = fmaf(a3, bv.w, acc[3][3]);
  }

  float4 bvec = *(const float4*)(bias + n0 + tx * 4);
#pragma unroll
  for (int i = 0; i < 4; ++i) {
    size_t m = m0 + ty * 4 + i;
    __half2* dst = (__half2*)(Xg + m * NG + n0 + tx * 4);
    dst[0] = __halves2half2(__float2half(acc[i][0] + bvec.x),
                            __float2half(acc[i][1] + bvec.y));
    dst[1] = __halves2half2(__float2half(acc[i][2] + bvec.z),
                            __float2half(acc[i][3] + bvec.w));
  }
}

// ===========================================================================
// Mega kernel: 256 WGs, ONE per CU (dynamic LDS > 160KiB/2).
//   [0,64):    role A — L0 recurrence (waits flagX for cc>=LEAD), flag0/chunk
//   [64,192):  role C — per iter cc: Xg0(cc+LEAD) -> flagX, then wait
//              flag0(cc) -> Xg1(cc)=h0@Wx1^T+b1 (in place) -> flagC
//   [192,256): role B — L1 recurrence on Xg1 chunks (waits flagC>=2)
// Recurrence: v_dot2_f32_f16 inner product, 64 f16x2 weight regs/thread
// (fits the arch half of the unified RF -> no per-use register moves;
// measured best across 5 structural families, R1-R19).
// ===========================================================================

// ---- role A: layer-0 recurrence (4-chain dot2) ----
__device__ __forceinline__ void roleA(int b, int n, char* smem,
    const __half* Xg, const float* __restrict__ Wh0,
    float* __restrict__ out, __half* hstream,
    unsigned* flag0, unsigned* flagX)
{
  const int j = n >> 2;
  const int p = n & 3;
  const bool tsel = (p == 2);

  h2_t wh[4][16];
#pragma unroll
  for (int g = 0; g < 4; ++g) {
    const float2* ph = (const float2*)(Wh0 + (size_t)(g * 128 + j) * HH + p * 32);
#pragma unroll
    for (int k = 0; k < 16; ++k) {
      float2 v = ph[k];
      wh[g][k][0] = (_Float16)v.x;
      wh[g][k][1] = (_Float16)v.y;
    }
  }

  _Float16(*hb)[HH] = (_Float16(*)[HH])smem;
  if (n < HH) {
    hb[0][n] = (_Float16)0.0f;
    hb[1][n] = (_Float16)0.0f;
  }
  float c = 0.0f, hv = 0.0f;
  __syncthreads();

  const __half* xs = Xg + (size_t)b * TT * NG + p * 128 + j;
  float* hT = out + (size_t)BB * TT * HH;
  float* cT = hT + 2 * BB * HH;
  __half* hsp = hstream + (size_t)b * TT * HH + j;

#pragma unroll 1
  for (int cc = 0; cc < NCH; ++cc) {
    if (cc >= LEAD) {
      if (n == 0) {
        while (aload(flagX + b * NCH + cc) < 2u) __builtin_amdgcn_s_sleep(1);
      }
      __syncthreads();
      __builtin_amdgcn_fence(__ATOMIC_ACQUIRE, "agent");
    }
    __half xg_c = xs[(size_t)(cc * CH) * NG];

#pragma unroll 1
    for (int s = 0; s < CH; ++s) {
      const int i = cc * CH + s;
      __half xg_n = (s + 1 < CH) ? xs[(size_t)(i + 1) * NG] : __float2half(0.0f);

      const char* H = (const char*)hb[i & 1] + p * 64;
      float a0 = 0.f, a1 = 0.f, a2 = 0.f, a3 = 0.f;
#pragma unroll
      for (int q = 0; q < 4; ++q) {
        LD4 u;
        u.f4 = *(const float4*)(H + q * 16);
#pragma unroll
        for (int t = 0; t < 4; ++t) {
          const int m = q * 4 + t;
          a0 = fdot2f(wh[0][m], u.h[t], a0);
          a1 = fdot2f(wh[1][m], u.h[t], a1);
          a2 = fdot2f(wh[2][m], u.h[t], a2);
          a3 = fdot2f(wh[3][m], u.h[t], a3);
        }
      }

      float k01 = (p & 1) ? a1 : a0;
      float u01 = (p & 1) ? a0 : a1;
      float r01 = k01 + dpp_xor1(u01);
      float k23 = (p & 1) ? a3 : a2;
      float u23 = (p & 1) ? a2 : a3;
      float r23 = k23 + dpp_xor1(u23);
      float kA = (p & 2) ? r23 : r01;
      float uA = (p & 2) ? r01 : r23;
      float sL = kA + dpp_xor2(uA);
      float aL = act_gate(sL + __half2float(xg_c), tsel);
      float fg = dpp_xor1(aL);
      float gg = dpp_xor2(aL);
      float og = dpp_xor2(fg);
      if (p == 0) {
        c = fg * c + aL * gg;
        hv = og * fast_tanh(c);
        _Float16 hf = (_Float16)hv;
        hb[(i & 1) ^ 1][j] = hf;
        *(_Float16*)(hsp + (size_t)i * HH) = hf;
      }
      bar_lds();
      xg_c = xg_n;
    }
    __syncthreads();   // drains hstream stores (vmcnt)
    if (n == 0) {
      __builtin_amdgcn_fence(__ATOMIC_RELEASE, "agent");
      atomicExch(flag0 + b * NCH + cc, 1u);
    }
  }

  if (p == 0) {
    hT[b * HH + j] = hv;
    cT[b * HH + j] = c;
  }
}

// ---- role C: Xg0(cc+LEAD) production then Xg1(cc) bridge GEMM ----
__device__ __forceinline__ void roleC(int cidx, int n, char* smem,
    __half* Xg, const __half* hstream, const float* __restrict__ x,
    const float* __restrict__ WT0, const float* __restrict__ b0,
    const float* __restrict__ WT1, const float* __restrict__ b1,
    unsigned* flag0, unsigned* flagC, unsigned* flagX)
{
  const int b = cidx >> 1;
  const int half = cidx & 1;
  h2_t(*As2)[68] = (h2_t(*)[68])smem;                    // [64][68] h2
  h2_t(*Bs2)[64] = (h2_t(*)[64])(smem + 64 * 68 * 4);    // [64][64] h2

  const int ty = n >> 4;
  const int tx = n & 15;
  const int mf = n >> 3;   // fill row
  const int sf = n & 7;    // fill segment

#pragma unroll 1
  for (int cc = 0; cc < NCH; ++cc) {
    // ======== part X0: Xg0 for chunk cc+LEAD (input-only, no waits) ========
    if (cc + LEAD < NCH) {
      const int t0x = (cc + LEAD) * CH + half * 64;
      {
        const float4* sx = (const float4*)(x + ((size_t)b * TT + t0x + mf) * II + sf * 16);
        float4 p0 = sx[0], p1 = sx[1], p2 = sx[2], p3 = sx[3];
        h2_t r[8];
        r[0][0] = (_Float16)p0.x; r[0][1] = (_Float16)p0.y;
        r[1][0] = (_Float16)p0.z; r[1][1] = (_Float16)p0.w;
        r[2][0] = (_Float16)p1.x; r[2][1] = (_Float16)p1.y;
        r[3][0] = (_Float16)p1.z; r[3][1] = (_Float16)p1.w;
        r[4][0] = (_Float16)p2.x; r[4][1] = (_Float16)p2.y;
        r[5][0] = (_Float16)p2.z; r[5][1] = (_Float16)p2.w;
        r[6][0] = (_Float16)p3.x; r[6][1] = (_Float16)p3.y;
        r[7][0] = (_Float16)p3.z; r[7][1] = (_Float16)p3.w;
        *(uint4*)&As2[mf][sf * 8] = *(uint4*)&r[0];
        *(uint4*)&As2[mf][sf * 8 + 4] = *(uint4*)&r[4];
      }
#pragma unroll 1
      for (int nt = 0; nt < 8; ++nt) {
        __syncthreads();
        {
          const int kp = n >> 3, cg = n & 7;
          const float4* w0 = (const float4*)(WT0 + (size_t)(2 * kp) * NG + nt * 64 + cg * 8);
          const float4* w1 = (const float4*)(WT0 + (size_t)(2 * kp + 1) * NG + nt * 64 + cg * 8);
          float4 x0 = w0[0], x1 = w0[1];
          float4 y0 = w1[0], y1 = w1[1];
          h2_t r[8];
          r[0][0] = (_Float16)x0.x; r[0][1] = (_Float16)y0.x;
          r[1][0] = (_Float16)x0.y; r[1][1] = (_Float16)y0.y;
          r[2][0] = (_Float16)x0.z; r[2][1] = (_Float16)y0.z;
          r[3][0] = (_Float16)x0.w; r[3][1] = (_Float16)y0.w;
          r[4][0] = (_Float16)x1.x; r[4][1] = (_Float16)y1.x;
          r[5][0] = (_Float16)x1.y; r[5][1] = (_Float16)y1.y;
          r[6][0] = (_Float16)x1.z; r[6][1] = (_Float16)y1.z;
          r[7][0] = (_Float16)x1.w; r[7][1] = (_Float16)y1.w;
          *(uint4*)&Bs2[kp][cg * 8] = *(uint4*)&r[0];
          *(uint4*)&Bs2[kp][cg * 8 + 4] = *(uint4*)&r[4];
        }
        __syncthreads();

        float acc[2][4];
#pragma unroll
        for (int r = 0; r < 2; ++r)
#pragma unroll
          for (int q = 0; q < 4; ++q) acc[r][q] = 0.0f;
#pragma unroll 4
        for (int k4 = 0; k4 < 16; ++k4) {
          LDB ua0, ua1;
          ua0.u4 = *(const uint4*)&As2[ty * 2][k4 * 4];
          ua1.u4 = *(const uint4*)&As2[ty * 2 + 1][k4 * 4];
#pragma unroll
          for (int t = 0; t < 4; ++t) {
            LDB ub;
            ub.u4 = *(const uint4*)&Bs2[k4 * 4 + t][tx * 4];
            acc[0][0] = fdot2f(ua0.h[t], ub.h[0], acc[0][0]);
            acc[0][1] = fdot2f(ua0.h[t], ub.h[1], acc[0][1]);
            acc[0][2] = fdot2f(ua0.h[t], ub.h[2], acc[0][2]);
            acc[0][3] = fdot2f(ua0.h[t], ub.h[3], acc[0][3]);
            acc[1][0] = fdot2f(ua1.h[t], ub.h[0], acc[1][0]);
            acc[1][1] = fdot2f(ua1.h[t], ub.h[1], acc[1][1]);
            acc[1][2] = fdot2f(ua1.h[t], ub.h[2], acc[1][2]);
            acc[1][3] = fdot2f(ua1.h[t], ub.h[3], acc[1][3]);
          }
        }
        const int col = nt * 64 + tx * 4;
        float4 bv = *(const float4*)(b0 + col);
#pragma unroll
        for (int r = 0; r < 2; ++r) {
          __half2* d = (__half2*)(Xg + ((size_t)b * TT + t0x + ty * 2 + r) * NG + col);
          d[0] = __halves2half2(__float2half(acc[r][0] + bv.x),
                                __float2half(acc[r][1] + bv.y));
          d[1] = __halves2half2(__float2half(acc[r][2] + bv.z),
                                __float2half(acc[r][3] + bv.w));
        }
      }
      __syncthreads();   // drain Xg0 stores + protect As2
      if (n == 0) {
        __builtin_amdgcn_fence(__ATOMIC_RELEASE, "agent");
        atomicAdd(flagX + b * NCH + cc + LEAD, 1u);
      }
    }

    // ======== part X1: Xg1 for chunk cc (waits on h0) ========
    if (n == 0) {
      while (aload(flag0 + b * NCH + cc) < 1u) __builtin_amdgcn_s_sleep(8);
    }
    __syncthreads();
    __builtin_amdgcn_fence(__ATOMIC_ACQUIRE, "agent");

    const int t0 = cc * CH + half * 64;
    {
      const uint4* src = (const uint4*)(hstream + ((size_t)b * TT + t0 + mf) * HH + sf * 16);
      uint4 v0 = src[0], v1 = src[1];
      *(uint4*)&As2[mf][sf * 8] = v0;
      *(uint4*)&As2[mf][sf * 8 + 4] = v1;
    }
#pragma unroll 1
    for (int nt = 0; nt < 8; ++nt) {
      __syncthreads();
      {
        const int kp = n >> 3, cg = n & 7;
        const float4* w0 = (const float4*)(WT1 + (size_t)(2 * kp) * NG + nt * 64 + cg * 8);
        const float4* w1 = (const float4*)(WT1 + (size_t)(2 * kp + 1) * NG + nt * 64 + cg * 8);
        float4 x0 = w0[0], x1 = w0[1];
        float4 y0 = w1[0], y1 = w1[1];
        h2_t r[8];
        r[0][0] = (_Float16)x0.x; r[0][1] = (_Float16)y0.x;
        r[1][0] = (_Float16)x0.y; r[1][1] = (_Float16)y0.y;
        r[2][0] = (_Float16)x0.z; r[2][1] = (_Float16)y0.z;
        r[3][0] = (_Float16)x0.w; r[3][1] = (_Float16)y0.w;
        r[4][0] = (_Float16)x1.x; r[4][1] = (_Float16)y1.x;
        r[5][0] = (_Float16)x1.y; r[5][1] = (_Float16)y1.y;
        r[6][0] = (_Float16)x1.z; r[6][1] = (_Float16)y1.z;
        r[7][0] = (_Float16)x1.w; r[7][1] = (_Float16)y1.w;
        *(uint4*)&Bs2[kp][cg * 8] = *(uint4*)&r[0];
        *(uint4*)&Bs2[kp][cg * 8 + 4] = *(uint4*)&r[4];
      }
      __syncthreads();

      float acc[2][4];
#pragma unroll
      for (int r = 0; r < 2; ++r)
#pragma unroll
        for (int q = 0; q < 4; ++q) acc[r][q] = 0.0f;
#pragma unroll 4
      for (int k4 = 0; k4 < 16; ++k4) {
        LDB ua0, ua1;
        ua0.u4 = *(const uint4*)&As2[ty * 2][k4 * 4];
        ua1.u4 = *(const uint4*)&As2[ty * 2 + 1][k4 * 4];
#pragma unroll
        for (int t = 0; t < 4; ++t) {
          LDB ub;
          ub.u4 = *(const uint4*)&Bs2[k4 * 4 + t][tx * 4];
          acc[0][0] = fdot2f(ua0.h[t], ub.h[0], acc[0][0]);
          acc[0][1] = fdot2f(ua0.h[t], ub.h[1], acc[0][1]);
          acc[0][2] = fdot2f(ua0.h[t], ub.h[2], acc[0][2]);
          acc[0][3] = fdot2f(ua0.h[t], ub.h[3], acc[0][3]);
          acc[1][0] = fdot2f(ua1.h[t], ub.h[0], acc[1][0]);
          acc[1][1] = fdot2f(ua1.h[t], ub.h[1], acc[1][1]);
          acc[1][2] = fdot2f(ua1.h[t], ub.h[2], acc[1][2]);
          acc[1][3] = fdot2f(ua1.h[t], ub.h[3], acc[1][3]);
        }
      }
      const int col = nt * 64 + tx * 4;
      float4 bv = *(const float4*)(b1 + col);
#pragma unroll
      for (int r = 0; r < 2; ++r) {
        __half2* d = (__half2*)(Xg + ((size_t)b * TT + t0 + ty * 2 + r) * NG + col);
        d[0] = __halves2half2(__float2half(acc[r][0] + bv.x),
                              __float2half(acc[r][1] + bv.y));
        d[1] = __halves2half2(__float2half(acc[r][2] + bv.z),
                              __float2half(acc[r][3] + bv.w));
      }
    }
    __syncthreads();
    if (n == 0) {
      __builtin_amdgcn_fence(__ATOMIC_RELEASE, "agent");
      atomicAdd(flagC + b * NCH + cc, 1u);
    }
  }
}

// ---- role B: layer-1 recurrence (4-chain dot2) ----
__device__ __forceinline__ void roleB(int b, int n, char* smem,
    const __half* Xg, const float* __restrict__ Wh1,
    float* __restrict__ out, unsigned* flagC)
{
  const int j = n >> 2;
  const int p = n & 3;
  const bool tsel = (p == 2);

  h2_t wh[4][16];
#pragma unroll
  for (int g = 0; g < 4; ++g) {
    const float2* ph = (const float2*)(Wh1 + (size_t)(g * 128 + j) * HH + p * 32);
#pragma unroll
    for (int k = 0; k < 16; ++k) {
      float2 v = ph[k];
      wh[g][k][0] = (_Float16)v.x;
      wh[g][k][1] = (_Float16)v.y;
    }
  }

  _Float16(*hb)[HH] = (_Float16(*)[HH])smem;
  if (n < HH) {
    hb[0][n] = (_Float16)0.0f;
    hb[1][n] = (_Float16)0.0f;
  }
  float c = 0.0f, hv = 0.0f;
  __syncthreads();

  const __half* xs = Xg + (size_t)b * TT * NG + p * 128 + j;
  float* outp = out + (size_t)b * TT * HH;
  float* hT = out + (size_t)BB * TT * HH;
  float* cT = hT + 2 * BB * HH;

#pragma unroll 1
  for (int cc = 0; cc < NCH; ++cc) {
    if (n == 0) {
      while (aload(flagC + b * NCH + cc) < 2u) __builtin_amdgcn_s_sleep(8);
    }
    __syncthreads();
    __builtin_amdgcn_fence(__ATOMIC_ACQUIRE, "agent");

    __half xg_c = xs[(size_t)(cc * CH) * NG];
#pragma unroll 1
    for (int s = 0; s < CH; ++s) {
      const int i = cc * CH + s;
      __half xg_n = (s + 1 < CH) ? xs[(size_t)(i + 1) * NG] : __float2half(0.0f);

      const char* H = (const char*)hb[i & 1] + p * 64;
      float a0 = 0.f, a1 = 0.f, a2 = 0.f, a3 = 0.f;
#pragma unroll
      for (int q = 0; q < 4; ++q) {
        LD4 u;
        u.f4 = *(const float4*)(H + q * 16);
#pragma unroll
        for (int t = 0; t < 4; ++t) {
          const int m = q * 4 + t;
          a0 = fdot2f(wh[0][m], u.h[t], a0);
          a1 = fdot2f(wh[1][m], u.h[t], a1);
          a2 = fdot2f(wh[2][m], u.h[t], a2);
          a3 = fdot2f(wh[3][m], u.h[t], a3);
        }
      }

      float k01 = (p & 1) ? a1 : a0;
      float u01 = (p & 1) ? a0 : a1;
      float r01 = k01 + dpp_xor1(u01);
      float k23 = (p & 1) ? a3 : a2;
      float u23 = (p & 1) ? a2 : a3;
      float r23 = k23 + dpp_xor1(u23);
      float kA = (p & 2) ? r23 : r01;
      float uA = (p & 2) ? r01 : r23;
      float sL = kA + dpp_xor2(uA);
      float aL = act_gate(sL + __half2float(xg_c), tsel);
      float fg = dpp_xor1(aL);
      float gg = dpp_xor2(aL);
      float og = dpp_xor2(fg);
      if (p == 0) {
        c = fg * c + aL * gg;
        hv = og * fast_tanh(c);
        hb[(i & 1) ^ 1][j] = (_Float16)hv;
        outp[(size_t)i * HH + j] = hv;
      }
      bar_lds();
      xg_c = xg_n;
    }
  }

  if (p == 0) {
    hT[BB * HH + b * HH + j] = hv;
    cT[BB * HH + b * HH + j] = c;
  }
}

__global__
__attribute__((amdgpu_flat_work_group_size(512, 512)))
void lstm_mega(__half* Xg, __half* hstream, const float* __restrict__ x,
               const float* __restrict__ Wh0,
               const float* __restrict__ Wh1,
               const float* __restrict__ WT0,
               const float* __restrict__ b0,
               const float* __restrict__ WT1,
               const float* __restrict__ b1,
               float* __restrict__ out,
               unsigned* flag0, unsigned* flagC, unsigned* flagX)
{
  extern __shared__ __align__(16) char smem[];   // DYN_LDS bytes: 1 WG/CU
  const int bid = blockIdx.x;
  const int n = threadIdx.x;
  if (bid < BB) {
    roleA(bid, n, smem, Xg, Wh0, out, hstream, flag0, flagX);
  } else if (bid < BB + 2 * BB) {
    roleC(bid - BB, n, smem, Xg, hstream, x, WT0, b0, WT1, b1,
          flag0, flagC, flagX);
  } else {
    roleB(bid - 3 * BB, n, smem, Xg, Wh1, out, flagC);
  }
}

// ---------------------------------------------------------------------------
extern "C" void kernel_launch(void* const* d_in, const int* in_sizes, int n_in,
                              void* d_out, int out_size, void* d_ws, size_t ws_size,
                              hipStream_t stream) {
  const float* x   = (const float*)d_in[0];
  const float* Wx0 = (const float*)d_in[1];
  const float* Wh0 = (const float*)d_in[2];
  const float* b0  = (const float*)d_in[3];
  const float* Wx1 = (const float*)d_in[4];
  const float* Wh1 = (const float*)d_in[5];
  const float* b1  = (const float*)d_in[6];
  float* out = (float*)d_out;

  // ws: Xg f16 [B*T][512] | hstream f16 [B*T][128] | WT0 | WT1 | flags x3
  char* base = (char*)d_ws;
  __half* Xg = (__half*)base;
  size_t off = (size_t)BB * TT * NG * sizeof(__half);      // 128 MB
  __half* hstream = (__half*)(base + off);
  off += (size_t)BB * TT * HH * sizeof(__half);            // +32 MB
  float* WT0 = (float*)(base + off);
  off += (size_t)II * NG * sizeof(float);
  float* WT1 = (float*)(base + off);
  off += (size_t)II * NG * sizeof(float);
  unsigned* flag0 = (unsigned*)(base + off);
  unsigned* flagC = flag0 + BB * NCH;
  unsigned* flagX = flagC + BB * NCH;

  hipFuncSetAttribute((const void*)lstm_mega,
                      hipFuncAttributeMaxDynamicSharedMemorySize, DYN_LDS);

  hipMemsetAsync(flag0, 0, 3 * (size_t)BB * NCH * sizeof(unsigned), stream);
  w_transpose2<<<512, 256, 0, stream>>>(Wx0, WT0, Wx1, WT1);
  // Prologue: Xg0 for chunks 0..LEAD-1 (rows [b*TT, b*TT+LEAD*CH))
  xg_gemm_pro<<<dim3(BB * 8, NG / 64), 256, 0, stream>>>(x, WT0, b0, Xg);
  lstm_mega<<<4 * BB, 512, DYN_LDS, stream>>>(Xg, hstream, x, Wh0, Wh1, WT0,
                                              b0, WT1, b1, out, flag0, flagC,
                                              flagX);
}